// Round 3
// baseline (1587.835 us; speedup 1.0000x reference)
//
#include <hip/hip_runtime.h>
#include <hip/hip_bf16.h>
#include <math.h>

#define N0 50000
#define E0 1600000
#define K1 40000
#define K2 32000
#define FEAT 128
#define HID 128
#define EMB 64
#define NCLS 10

#define RADIX_BINS 4096   // 12-bit digits, 4 passes over the 48-bit key

// CSR bucketed build: 128 dsts per bucket
#define NB 391            // ceil(50000 / 128)
#define PB_CH 8192        // edges per partition block
#define BCAP 5120         // LDS staging capacity (avg bucket = 4096, +16 sigma)

typedef __bf16 v8bf __attribute__((ext_vector_type(8)));
typedef __bf16 v4bf __attribute__((ext_vector_type(4)));
typedef float  v4f  __attribute__((ext_vector_type(4)));

static __device__ __forceinline__ unsigned f2key(float f) {
    unsigned u = __float_as_uint(f);
    return (u & 0x80000000u) ? ~u : (u | 0x80000000u);
}

// ---------- dtype detection ----------
__global__ void detect_dtype_kernel(const unsigned* __restrict__ w, int n, int* __restrict__ flag) {
    __shared__ int tot;
    if (threadIdx.x == 0) tot = 0;
    __syncthreads();
    int cnt = 0;
    for (int i = threadIdx.x; i < n; i += 256) {
        unsigned lo = w[i] & 0xFFFFu;
        unsigned e = (lo >> 7) & 0xFFu;
        cnt += (e >= 143);
    }
    atomicAdd(&tot, cnt);
    __syncthreads();
    if (threadIdx.x == 0) flag[0] = (tot > n / 8) ? 1 : 0;  // 1 = f32, 0 = bf16
}

static __device__ __forceinline__ float load_as_f32(const void* in, long long i, int isF32) {
    if (isF32) return ((const float*)in)[i];
    unsigned short h = ((const unsigned short*)in)[i];
    return __uint_as_float(((unsigned)h) << 16);
}

// x: one pass -> f32 + (hi,lo)
__global__ void x_convert_kernel(const void* __restrict__ in, float* __restrict__ xf,
                                 __bf16* __restrict__ hi, __bf16* __restrict__ lo, int n,
                                 const int* __restrict__ flag) {
    int i = blockIdx.x * 256 + threadIdx.x;
    if (i >= n) return;
    float v = load_as_f32(in, i, *flag);
    __bf16 h = (__bf16)v;
    xf[i] = v; hi[i] = h; lo[i] = (__bf16)(v - (float)h);
}

// batched weight splits (10 tensors in one launch)
struct SplitJob { const void* src; __bf16* hi; __bf16* lo; int n; };
struct SplitJobs { SplitJob j[10]; };
__global__ void split_all_kernel(SplitJobs jobs, const int* __restrict__ flag) {
    SplitJob jb = jobs.j[blockIdx.y];
    int i = blockIdx.x * 256 + threadIdx.x;
    if (i >= jb.n) return;
    float v = load_as_f32(jb.src, i, *flag);
    __bf16 h = (__bf16)v;
    jb.hi[i] = h; jb.lo[i] = (__bf16)(v - (float)h);
}

// batched small f32 conversions (9 tensors, one block each)
struct F32Job { const void* src; float* dst; int n; };
struct F32Jobs { F32Job j[9]; };
__global__ void f32_all_kernel(F32Jobs jobs, const int* __restrict__ flag) {
    F32Job jb = jobs.j[blockIdx.x];
    for (int i = threadIdx.x; i < jb.n; i += 256) jb.dst[i] = load_as_f32(jb.src, i, *flag);
}

// ---------- CSR graph0: degree count ----------
__global__ void deg_count_kernel(const int* __restrict__ dst, int E, int* __restrict__ deg) {
    int e = blockIdx.x * 256 + threadIdx.x;
    if (e >= E) return;
    atomicAdd(&deg[dst[e]], 1);
}

// exclusive scan; also writes cursor (= rowptr copy)
__global__ void exclusive_scan_kernel(const int* __restrict__ deg, int* __restrict__ rowptr,
                                      int* __restrict__ cursor, int M) {
    __shared__ int part[1024];
    int t = threadIdx.x;
    int per = (M + 1023) / 1024;
    int s = 0;
    for (int k = 0; k < per; ++k) { int idx = t * per + k; if (idx < M) s += deg[idx]; }
    part[t] = s;
    __syncthreads();
    for (int off = 1; off < 1024; off <<= 1) {
        int v = 0;
        if (t >= off) v = part[t - off];
        __syncthreads();
        if (t >= off) part[t] += v;
        __syncthreads();
    }
    int run = (t > 0) ? part[t - 1] : 0;
    for (int k = 0; k < per; ++k) {
        int idx = t * per + k;
        if (idx < M) { rowptr[idx] = run; cursor[idx] = run; run += deg[idx]; }
    }
    if (t == 1023) rowptr[M] = part[1023];
}

// ---------- CSR graph0: bucketed two-pass fill (write line-density fix) ----------
// Random 4B scatter costs 64B write-allocate per edge (measured 101MB traffic for
// a 6.4MB payload, 135us). Bucket-major packed pairs + LDS-staged per-bucket fill
// makes every global write a full coalesced line.
__global__ void bcur_init_kernel(const int* __restrict__ rp, int* __restrict__ bcur) {
    int b = blockIdx.x * 256 + threadIdx.x;
    if (b < NB) bcur[b] = rp[b << 7];
}

__global__ void edge_partition_kernel(const int* __restrict__ src, const int* __restrict__ dst, int E,
                                      int* __restrict__ bcur, unsigned* __restrict__ pairBuf) {
    __shared__ int cnt[NB];
    __shared__ int bas[NB];
    for (int b = threadIdx.x; b < NB; b += 256) cnt[b] = 0;
    __syncthreads();
    int e0 = blockIdx.x * PB_CH;
    int e1 = E < e0 + PB_CH ? E : e0 + PB_CH;
    for (int e = e0 + threadIdx.x; e < e1; e += 256)
        atomicAdd(&cnt[dst[e] >> 7], 1);
    __syncthreads();
    for (int b = threadIdx.x; b < NB; b += 256) {
        int c = cnt[b];
        bas[b] = c ? atomicAdd(&bcur[b], c) : 0;
        cnt[b] = 0;
    }
    __syncthreads();
    for (int e = e0 + threadIdx.x; e < e1; e += 256) {
        int s = src[e], d = dst[e];
        int b = d >> 7;
        int r = atomicAdd(&cnt[b], 1);
        pairBuf[bas[b] + r] = ((unsigned)(d & 127) << 16) | (unsigned)s;  // both < 65536
    }
}

__global__ void bucket_csr_fill_kernel(const unsigned* __restrict__ pairBuf, const int* __restrict__ rp,
                                       int Mrows, int* __restrict__ cols, int* __restrict__ gcursor) {
    int b = blockIdx.x;
    int d0 = b << 7;
    int d1 = d0 + 128; if (d1 > Mrows) d1 = Mrows;
    int segBase = rp[d0], segEnd = rp[d1];
    int size = segEnd - segBase;
    __shared__ int cur[128];
    __shared__ int stage[BCAP];
    if (size <= BCAP) {
        for (int j = threadIdx.x; j < d1 - d0; j += 256) cur[j] = rp[d0 + j] - segBase;
        __syncthreads();
        for (int t = threadIdx.x; t < size; t += 256) {
            unsigned p = pairBuf[segBase + t];
            int pos = atomicAdd(&cur[p >> 16], 1);
            stage[pos] = (int)(p & 0xFFFFu);
        }
        __syncthreads();
        for (int t = threadIdx.x; t < size; t += 256) cols[segBase + t] = stage[t];
    } else {  // statistically unreachable; correctness fallback
        for (int t = threadIdx.x; t < size; t += 256) {
            unsigned p = pairBuf[segBase + t];
            int pos = atomicAdd(&gcursor[d0 + (int)(p >> 16)], 1);
            cols[pos] = (int)(p & 0xFFFFu);
        }
    }
}

// ---------- CSR graph k+1 from CSR k (filter through monotonic mapping) ----------
__global__ void deg_filter_kernel(const int* __restrict__ rowptr, const int* __restrict__ cols,
                                  const int* __restrict__ map, int Mold, int* __restrict__ deg) {
    int d = blockIdx.x * 256 + threadIdx.x;
    if (d >= Mold) return;
    int nd = map[d];
    if (nd < 0) return;
    int b = rowptr[d], e = rowptr[d + 1];
    int c = 0;
    for (int j = b; j < e; ++j) c += (map[cols[j]] >= 0);
    deg[nd] = c;
}

__global__ void csr_filter_fill_kernel(const int* __restrict__ rowptr, const int* __restrict__ cols,
                                       const int* __restrict__ map, int Mold,
                                       const int* __restrict__ newrp, int* __restrict__ ncols) {
    int d = blockIdx.x * 256 + threadIdx.x;
    if (d >= Mold) return;
    int nd = map[d];
    if (nd < 0) return;
    int w = newrp[nd];
    int b = rowptr[d], e = rowptr[d + 1];
    for (int j = b; j < e; ++j) {
        int ns = map[cols[j]];
        if (ns >= 0) ncols[w++] = ns;
    }
}

// ---------- gather aggregation: f32 gather/accumulate, hi/lo bf16 out ----------
template<int C>
__global__ void aggregate_kernel(const int* __restrict__ rowptr, const int* __restrict__ cols,
                                 const float* __restrict__ x, __bf16* __restrict__ aggHi,
                                 __bf16* __restrict__ aggLo, int M) {
    const int CH = C / 4;
    const int NPB = 256 / CH;
    int n = blockIdx.x * NPB + threadIdx.x / CH;
    int c4 = threadIdx.x % CH;
    if (n >= M) return;
    int b = rowptr[n], e = rowptr[n + 1];
    float4 s = {0.f, 0.f, 0.f, 0.f};
    for (int j = b; j < e; ++j) {
        int src = cols[j];
        float4 v = ((const float4*)(x + (size_t)src * C))[c4];
        s.x += v.x; s.y += v.y; s.z += v.z; s.w += v.w;
    }
    v4bf h, l;
    h[0] = (__bf16)s.x; l[0] = (__bf16)(s.x - (float)h[0]);
    h[1] = (__bf16)s.y; l[1] = (__bf16)(s.y - (float)h[1]);
    h[2] = (__bf16)s.z; l[2] = (__bf16)(s.z - (float)h[2]);
    h[3] = (__bf16)s.w; l[3] = (__bf16)(s.w - (float)h[3]);
    *(v4bf*)(aggHi + (size_t)n * C + c4 * 4) = h;
    *(v4bf*)(aggLo + (size_t)n * C + c4 * 4) = l;
}

// ---------- split-precision MFMA dual linear + bias + relu ----------
template<int Cin, int Cout>
__global__ void linear_mfma_kernel(int M,
                                   const __bf16* __restrict__ Ahi, const __bf16* __restrict__ Alo,
                                   const __bf16* __restrict__ WaHi, const __bf16* __restrict__ WaLo,
                                   const __bf16* __restrict__ Bhi, const __bf16* __restrict__ Blo,
                                   const __bf16* __restrict__ WbHi, const __bf16* __restrict__ WbLo,
                                   const float* __restrict__ bias, float* __restrict__ outF) {
    constexpr int NG = Cout / 16;
    int wave = threadIdx.x >> 6;
    int lane = threadIdx.x & 63;
    int m = lane & 15, quad = lane >> 4;
    int row0 = blockIdx.x * 64 + wave * 16;
    int ra = row0 + m; if (ra > M - 1) ra = M - 1;

    v4f acc[NG];
#pragma unroll
    for (int g = 0; g < NG; ++g) acc[g] = (v4f){0.f, 0.f, 0.f, 0.f};

#pragma unroll
    for (int ks = 0; ks < Cin / 32; ++ks) {
        size_t aoff = (size_t)ra * Cin + ks * 32 + quad * 8;
        v8bf ah = *(const v8bf*)(Ahi + aoff);
        v8bf al = *(const v8bf*)(Alo + aoff);
#pragma unroll
        for (int g = 0; g < NG; ++g) {
            size_t woff = (size_t)(g * 16 + m) * Cin + ks * 32 + quad * 8;
            v8bf bh = *(const v8bf*)(WaHi + woff);
            v8bf bl = *(const v8bf*)(WaLo + woff);
            acc[g] = __builtin_amdgcn_mfma_f32_16x16x32_bf16(ah, bh, acc[g], 0, 0, 0);
            acc[g] = __builtin_amdgcn_mfma_f32_16x16x32_bf16(ah, bl, acc[g], 0, 0, 0);
            acc[g] = __builtin_amdgcn_mfma_f32_16x16x32_bf16(al, bh, acc[g], 0, 0, 0);
        }
    }
#pragma unroll
    for (int ks = 0; ks < Cin / 32; ++ks) {
        size_t aoff = (size_t)ra * Cin + ks * 32 + quad * 8;
        v8bf ah = *(const v8bf*)(Bhi + aoff);
        v8bf al = *(const v8bf*)(Blo + aoff);
#pragma unroll
        for (int g = 0; g < NG; ++g) {
            size_t woff = (size_t)(g * 16 + m) * Cin + ks * 32 + quad * 8;
            v8bf bh = *(const v8bf*)(WbHi + woff);
            v8bf bl = *(const v8bf*)(WbLo + woff);
            acc[g] = __builtin_amdgcn_mfma_f32_16x16x32_bf16(ah, bh, acc[g], 0, 0, 0);
            acc[g] = __builtin_amdgcn_mfma_f32_16x16x32_bf16(ah, bl, acc[g], 0, 0, 0);
            acc[g] = __builtin_amdgcn_mfma_f32_16x16x32_bf16(al, bh, acc[g], 0, 0, 0);
        }
    }

    // C/D layout: col = lane&15, row = quad*4 + reg
#pragma unroll
    for (int g = 0; g < NG; ++g) {
        int col = g * 16 + m;
        float bv = bias[col];
#pragma unroll
        for (int r = 0; r < 4; ++r) {
            int row = row0 + quad * 4 + r;
            if (row < M) outF[(size_t)row * Cout + col] = fmaxf(acc[g][r] + bv, 0.f);
        }
    }
}

// ---------- pooling score (fused 48-bit selection key build) ----------
// key = (f2key(score) << 16) | (~i & 0xFFFF)   -- valid since N <= 65536;
// preserves exact smaller-index-first tie-break of jax.lax.top_k.
template<int C>
__global__ void score_kernel(const float* __restrict__ xin, const float* __restrict__ w,
                             int M, float* __restrict__ score, unsigned long long* __restrict__ keys) {
    int row = blockIdx.x * 4 + (threadIdx.x >> 6);
    int lane = threadIdx.x & 63;
    if (row >= M) return;
    float p = 0.f, q = 0.f;
#pragma unroll
    for (int c = lane; c < C; c += 64) {
        float wc = w[c];
        float xc = xin[(size_t)row * C + c];
        p += xc * wc; q += wc * wc;
    }
#pragma unroll
    for (int off = 32; off >= 1; off >>= 1) {
        p += __shfl_xor(p, off, 64);
        q += __shfl_xor(q, off, 64);
    }
    if (lane == 0) {
        float arg = p / sqrtf(q);
        float sc = (float)tanh((double)arg);
        score[row] = sc;
        keys[row] = ((unsigned long long)f2key(sc) << 16) |
                    (unsigned long long)(0xFFFFu ^ (unsigned)row);
    }
}

// ---------- radix-select top-K threshold (4 passes of 12-bit digits on 48-bit keys) ----------
// LDS-privatized histogram (tanh clusters scores; global same-address atomics serialize).
struct SelCtl { unsigned long long prefix; int kRem; int counter; };

__global__ void radix_hist_kernel(const unsigned long long* __restrict__ keys, int N,
                                  int* __restrict__ hist, const SelCtl* __restrict__ ctl, int pass) {
    __shared__ int lh[RADIX_BINS];
    for (int b = threadIdx.x; b < RADIX_BINS; b += 256) lh[b] = 0;
    __syncthreads();
    int shift = 36 - 12 * pass;                 // pass0: bits[36:48) ... pass3: bits[0:12)
    unsigned long long pref = (pass > 0) ? ctl->prefix : 0ull;
    for (int i = blockIdx.x * 256 + threadIdx.x; i < N; i += gridDim.x * 256) {
        unsigned long long key = keys[i];
        if (pass > 0 && (key >> (shift + 12)) != pref) continue;
        atomicAdd(&lh[(int)((key >> shift) & 0xFFFull)], 1);
    }
    __syncthreads();
    for (int b = threadIdx.x; b < RADIX_BINS; b += 256) {
        int c = lh[b];
        if (c) atomicAdd(&hist[b], c);          // <=gridDim adds per address
    }
}

// single block, 1024 threads (4 bins each); finds digit containing the kRem-th
// largest key, updates ctl, and re-zeros the histogram for the next pass.
__global__ void radix_select_kernel(int* __restrict__ hist, SelCtl* __restrict__ ctl,
                                    int K, int pass) {
    __shared__ int part[1024];
    int t = threadIdx.x;
    int kRem = (pass == 0) ? K : ctl->kRem;
    unsigned long long oldPrefix = (pass == 0) ? 0ull : ctl->prefix;
    int base = t * 4;
    int h0 = hist[base], h1 = hist[base + 1], h2 = hist[base + 2], h3 = hist[base + 3];
    int tot = h0 + h1 + h2 + h3;
    part[t] = tot;
    __syncthreads();
    // inclusive suffix sum: part[t] = sum_{t' >= t} tot(t')
    for (int off = 1; off < 1024; off <<= 1) {
        int v = (t + off < 1024) ? part[t + off] : 0;
        __syncthreads();
        part[t] += v;
        __syncthreads();
    }
    int sExcl = part[t] - tot;                  // keys with digit in a strictly higher chunk
    if (sExcl < kRem && kRem <= sExcl + tot) {  // crossing chunk (unique; tot>0 here)
        int c = sExcl;
        int hv[4] = {h0, h1, h2, h3};
        for (int k = 3; k >= 0; --k) {
            int h = hv[k];
            if (c + h >= kRem) {
                ctl->prefix = (oldPrefix << 12) | (unsigned long long)(base + k);
                ctl->kRem = kRem - c;
                ctl->counter = 0;
                break;
            }
            c += h;
        }
    }
    // re-zero for the next histogram pass
    hist[base] = 0; hist[base + 1] = 0; hist[base + 2] = 0; hist[base + 3] = 0;
}

// ---------- monotonic keep/compact (makes CSR-filter writes sequential) ----------
__global__ void mark_keep_kernel(const unsigned long long* __restrict__ keys, int N,
                                 const SelCtl* __restrict__ ctl, int* __restrict__ keep) {
    int i = blockIdx.x * 256 + threadIdx.x;
    if (i < N) keep[i] = (keys[i] >= ctl->prefix) ? 1 : 0;
}

__global__ void finalize_map_kernel(const int* __restrict__ keep, const int* __restrict__ pos,
                                    int N, int* __restrict__ perm, int* __restrict__ mapping) {
    int i = blockIdx.x * 256 + threadIdx.x;
    if (i >= N) return;
    if (keep[i]) { int r = pos[i]; perm[r] = i; mapping[i] = r; }
    else mapping[i] = -1;
}

// xp[j] = x[perm[j]] * score[perm[j]]  -> f32 + (hi,lo)
template<int C>
__global__ void pool_apply_kernel(const float* __restrict__ xin, const float* __restrict__ score,
                                  const int* __restrict__ perm, float* __restrict__ xpF,
                                  __bf16* __restrict__ xpHi, __bf16* __restrict__ xpLo, int K) {
    const int CH = C / 4;
    int tid = blockIdx.x * 256 + threadIdx.x;
    int j = tid / CH, c4 = tid % CH;
    if (j >= K) return;
    int src = perm[j];
    float s = score[src];
    float4 v = ((const float4*)(xin + (size_t)src * C))[c4];
    v.x *= s; v.y *= s; v.z *= s; v.w *= s;
    ((float4*)(xpF + (size_t)j * C))[c4] = v;
    v4bf h, l;
    h[0] = (__bf16)v.x; l[0] = (__bf16)(v.x - (float)h[0]);
    h[1] = (__bf16)v.y; l[1] = (__bf16)(v.y - (float)h[1]);
    h[2] = (__bf16)v.z; l[2] = (__bf16)(v.z - (float)h[2]);
    h[3] = (__bf16)v.w; l[3] = (__bf16)(v.w - (float)h[3]);
    *(v4bf*)(xpHi + (size_t)j * C + c4 * 4) = h;
    *(v4bf*)(xpLo + (size_t)j * C + c4 * 4) = l;
}

// u[j] = base[j] + (mapping[j]>=0 ? deep[mapping[j]] : 0)  -> f32 + (hi,lo); uF may alias base
template<int C>
__global__ void unpool_add_kernel(const float* __restrict__ base, const float* __restrict__ deep,
                                  const int* __restrict__ mapping, float* __restrict__ uF,
                                  __bf16* __restrict__ uHi, __bf16* __restrict__ uLo, int M) {
    const int CH = C / 4;
    int tid = blockIdx.x * 256 + threadIdx.x;
    int j = tid / CH, c4 = tid % CH;
    if (j >= M) return;
    float4 v = ((const float4*)(base + (size_t)j * C))[c4];
    int m = mapping[j];
    if (m >= 0) {
        float4 d = ((const float4*)(deep + (size_t)m * C))[c4];
        v.x += d.x; v.y += d.y; v.z += d.z; v.w += d.w;
    }
    ((float4*)(uF + (size_t)j * C))[c4] = v;
    v4bf h, l;
    h[0] = (__bf16)v.x; l[0] = (__bf16)(v.x - (float)h[0]);
    h[1] = (__bf16)v.y; l[1] = (__bf16)(v.y - (float)h[1]);
    h[2] = (__bf16)v.z; l[2] = (__bf16)(v.z - (float)h[2]);
    h[3] = (__bf16)v.w; l[3] = (__bf16)(v.w - (float)h[3]);
    *(v4bf*)(uHi + (size_t)j * C + c4 * 4) = h;
    *(v4bf*)(uLo + (size_t)j * C + c4 * 4) = l;
}

__global__ void head_kernel(const float* __restrict__ x5, const float* __restrict__ lw,
                            const float* __restrict__ lb, void* __restrict__ out, int M,
                            const int* __restrict__ flag) {
    int row = blockIdx.x * 4 + (threadIdx.x >> 6);
    int lane = threadIdx.x & 63;
    if (row >= M) return;
    float a0 = x5[(size_t)row * 128 + lane];
    float a1 = x5[(size_t)row * 128 + 64 + lane];
    float d[NCLS];
#pragma unroll
    for (int o = 0; o < NCLS; ++o) {
        float p = a0 * lw[o * 128 + lane] + a1 * lw[o * 128 + 64 + lane];
#pragma unroll
        for (int off = 32; off >= 1; off >>= 1) p += __shfl_xor(p, off, 64);
        d[o] = p + lb[o];
    }
    float mx = d[0];
#pragma unroll
    for (int o = 1; o < NCLS; ++o) mx = fmaxf(mx, d[o]);
    float s = 0.f;
#pragma unroll
    for (int o = 0; o < NCLS; ++o) s += expf(d[o] - mx);
    float lse = mx + logf(s);
    if (lane < NCLS) {
        float v = d[0];
#pragma unroll
        for (int o = 1; o < NCLS; ++o) if (lane == o) v = d[o];
        float r = v - lse;
        if (*flag) ((float*)out)[(size_t)row * NCLS + lane] = r;
        else ((__hip_bfloat16*)out)[(size_t)row * NCLS + lane] = __float2bfloat16(r);
    }
}

extern "C" void kernel_launch(void* const* d_in, const int* in_sizes, int n_in,
                              void* d_out, int out_size, void* d_ws, size_t ws_size,
                              hipStream_t stream) {
    const void* x_raw   = d_in[0];
    const int*  ei      = (const int*)d_in[1];
    const void* w1_rel  = d_in[2];
    const void* w1_root = d_in[3];
    const void* b1      = d_in[4];
    const void* p1w     = d_in[5];
    const void* w2_rel  = d_in[6];
    const void* w2_root = d_in[7];
    const void* b2      = d_in[8];
    const void* p2w     = d_in[9];
    const void* w3_rel  = d_in[10];
    const void* w3_root = d_in[11];
    const void* b3      = d_in[12];
    const void* w4_rel  = d_in[13];
    const void* w4_root = d_in[14];
    const void* b4      = d_in[15];
    const void* w5_rel  = d_in[16];
    const void* w5_root = d_in[17];
    const void* b5      = d_in[18];
    const void* lw      = d_in[19];
    const void* lb      = d_in[20];

    char* base = (char*)d_ws;
    size_t off = 0;
    auto alloc = [&](size_t bytes) -> void* {
        void* p = base + off;
        off = (off + bytes + 255) & ~(size_t)255;
        return p;
    };
    int* flag = (int*)alloc(256);
    __bf16* w1rHi = (__bf16*)alloc(HID * FEAT * 2); __bf16* w1rLo = (__bf16*)alloc(HID * FEAT * 2);
    __bf16* w1tHi = (__bf16*)alloc(HID * FEAT * 2); __bf16* w1tLo = (__bf16*)alloc(HID * FEAT * 2);
    __bf16* w2rHi = (__bf16*)alloc(EMB * HID * 2);  __bf16* w2rLo = (__bf16*)alloc(EMB * HID * 2);
    __bf16* w2tHi = (__bf16*)alloc(EMB * HID * 2);  __bf16* w2tLo = (__bf16*)alloc(EMB * HID * 2);
    __bf16* w3rHi = (__bf16*)alloc(EMB * EMB * 2);  __bf16* w3rLo = (__bf16*)alloc(EMB * EMB * 2);
    __bf16* w3tHi = (__bf16*)alloc(EMB * EMB * 2);  __bf16* w3tLo = (__bf16*)alloc(EMB * EMB * 2);
    __bf16* w4rHi = (__bf16*)alloc(HID * EMB * 2);  __bf16* w4rLo = (__bf16*)alloc(HID * EMB * 2);
    __bf16* w4tHi = (__bf16*)alloc(HID * EMB * 2);  __bf16* w4tLo = (__bf16*)alloc(HID * EMB * 2);
    __bf16* w5rHi = (__bf16*)alloc(FEAT * HID * 2); __bf16* w5rLo = (__bf16*)alloc(FEAT * HID * 2);
    __bf16* w5tHi = (__bf16*)alloc(FEAT * HID * 2); __bf16* w5tLo = (__bf16*)alloc(FEAT * HID * 2);
    float* b1f = (float*)alloc(HID * 4);
    float* b2f = (float*)alloc(EMB * 4);
    float* b3f = (float*)alloc(EMB * 4);
    float* b4f = (float*)alloc(HID * 4);
    float* b5f = (float*)alloc(FEAT * 4);
    float* p1f = (float*)alloc(HID * 4);
    float* p2f = (float*)alloc(EMB * 4);
    float* lwf = (float*)alloc(NCLS * FEAT * 4);
    float* lbf = (float*)alloc(NCLS * 4);
    float* score = (float*)alloc((size_t)N0 * 4);
    unsigned long long* keys = (unsigned long long*)alloc((size_t)N0 * 8);
    int* hist = (int*)alloc((size_t)RADIX_BINS * 4);
    SelCtl* ctl = (SelCtl*)alloc(256);
    int* perm1 = (int*)alloc((size_t)K1 * 4);
    int* map1  = (int*)alloc((size_t)N0 * 4);
    int* perm2 = (int*)alloc((size_t)K2 * 4);
    int* map2  = (int*)alloc((size_t)K1 * 4);
    int* keep  = (int*)alloc((size_t)(N0 + 1) * 4);
    int* pos   = (int*)alloc((size_t)(N0 + 1) * 4);
    int* deg   = (int*)alloc((size_t)(N0 + 1) * 4);
    int* cursor= (int*)alloc((size_t)(N0 + 1) * 4);
    int* rp0   = (int*)alloc((size_t)(N0 + 1) * 4);
    int* rp1   = (int*)alloc((size_t)(K1 + 1) * 4);
    int* rp2   = (int*)alloc((size_t)(K2 + 1) * 4);
    int* bcur  = (int*)alloc((size_t)NB * 4);
    int* cols0 = (int*)alloc((size_t)E0 * 4);
    int* cols1 = (int*)alloc((size_t)E0 * 4);
    int* cols2 = (int*)alloc((size_t)E0 * 4);
    unsigned* pairBuf = (unsigned*)alloc((size_t)E0 * 4);
    // aliased activation arenas
    char*   arenaX  = (char*)alloc((size_t)N0 * 128 * 4);   // xf -> xp1f -> {xp2f,x3f} -> x4f -> x5f
    __bf16* arenaHi = (__bf16*)alloc((size_t)N0 * 128 * 2);
    __bf16* arenaLo = (__bf16*)alloc((size_t)N0 * 128 * 2);
    __bf16* aggHi   = (__bf16*)alloc((size_t)N0 * 128 * 2);
    __bf16* aggLo   = (__bf16*)alloc((size_t)N0 * 128 * 2);
    float*  x1f     = (float*)alloc((size_t)N0 * 128 * 4);  // persists; becomes u2 f32 in-place
    float*  x2f     = (float*)alloc((size_t)K1 * 64 * 4);   // persists; becomes u1 f32 in-place

    float* xf   = (float*)arenaX;
    float* xp1f = (float*)arenaX;
    float* xp2f = (float*)arenaX;
    float* x3f  = (float*)(arenaX + 8388608);
    float* x4f  = (float*)arenaX;
    float* x5f  = (float*)arenaX;
    __bf16 *xHi = arenaHi,  *xLo = arenaLo;
    __bf16 *xp1Hi = arenaHi, *xp1Lo = arenaLo;
    __bf16 *xp2Hi = arenaHi, *xp2Lo = arenaLo;
    __bf16 *u1Hi = arenaHi,  *u1Lo = arenaLo;
    __bf16 *u2Hi = arenaHi,  *u2Lo = arenaLo;
    float* u1f = x2f;

    const int* src0 = ei;
    const int* dst0 = ei + E0;

    auto g = [](long long n, int b) -> unsigned { return (unsigned)((n + b - 1) / b); };

    // ---- dtype detect + fused conversions ----
    detect_dtype_kernel<<<1, 256, 0, stream>>>((const unsigned*)x_raw, 4096, flag);
    hipMemsetAsync(hist, 0, (size_t)RADIX_BINS * 4, stream);  // selects re-zero after each pass
    x_convert_kernel<<<g((long long)N0 * FEAT, 256), 256, 0, stream>>>(x_raw, xf, xHi, xLo, N0 * FEAT, flag);
    {
        SplitJobs sj;
        sj.j[0] = {w1_rel,  w1rHi, w1rLo, HID * FEAT};
        sj.j[1] = {w1_root, w1tHi, w1tLo, HID * FEAT};
        sj.j[2] = {w2_rel,  w2rHi, w2rLo, EMB * HID};
        sj.j[3] = {w2_root, w2tHi, w2tLo, EMB * HID};
        sj.j[4] = {w3_rel,  w3rHi, w3rLo, EMB * EMB};
        sj.j[5] = {w3_root, w3tHi, w3tLo, EMB * EMB};
        sj.j[6] = {w4_rel,  w4rHi, w4rLo, HID * EMB};
        sj.j[7] = {w4_root, w4tHi, w4tLo, HID * EMB};
        sj.j[8] = {w5_rel,  w5rHi, w5rLo, FEAT * HID};
        sj.j[9] = {w5_root, w5tHi, w5tLo, FEAT * HID};
        dim3 grid(g(HID * FEAT, 256), 10);
        split_all_kernel<<<grid, 256, 0, stream>>>(sj, flag);
    }
    {
        F32Jobs fj;
        fj.j[0] = {b1, b1f, HID};
        fj.j[1] = {b2, b2f, EMB};
        fj.j[2] = {b3, b3f, EMB};
        fj.j[3] = {b4, b4f, HID};
        fj.j[4] = {b5, b5f, FEAT};
        fj.j[5] = {p1w, p1f, HID};
        fj.j[6] = {p2w, p2f, EMB};
        fj.j[7] = {lw, lwf, NCLS * FEAT};
        fj.j[8] = {lb, lbf, NCLS};
        f32_all_kernel<<<9, 256, 0, stream>>>(fj, flag);
    }

    // ---- CSR graph0 (bucketed two-pass build) ----
    hipMemsetAsync(deg, 0, (size_t)N0 * 4, stream);
    deg_count_kernel<<<g(E0, 256), 256, 0, stream>>>(dst0, E0, deg);
    exclusive_scan_kernel<<<1, 1024, 0, stream>>>(deg, rp0, cursor, N0);
    bcur_init_kernel<<<2, 256, 0, stream>>>(rp0, bcur);
    edge_partition_kernel<<<g(E0, PB_CH), 256, 0, stream>>>(src0, dst0, E0, bcur, pairBuf);
    bucket_csr_fill_kernel<<<NB, 256, 0, stream>>>(pairBuf, rp0, N0, cols0, cursor);

    // ---- Layer 1 ----
    aggregate_kernel<128><<<g(N0, 8), 256, 0, stream>>>(rp0, cols0, xf, aggHi, aggLo, N0);
    linear_mfma_kernel<128, 128><<<g(N0, 64), 256, 0, stream>>>(N0, aggHi, aggLo, w1rHi, w1rLo,
                                                                xHi, xLo, w1tHi, w1tLo, b1f, x1f);

    // ---- Pool 1 (radix-select top-K1, monotonic compaction) ----
    score_kernel<128><<<g(N0, 4), 256, 0, stream>>>(x1f, p1f, N0, score, keys);
    for (int pass = 0; pass < 4; ++pass) {
        radix_hist_kernel<<<64, 256, 0, stream>>>(keys, N0, hist, ctl, pass);
        radix_select_kernel<<<1, 1024, 0, stream>>>(hist, ctl, K1, pass);
    }
    mark_keep_kernel<<<g(N0, 256), 256, 0, stream>>>(keys, N0, ctl, keep);
    exclusive_scan_kernel<<<1, 1024, 0, stream>>>(keep, pos, cursor, N0);
    finalize_map_kernel<<<g(N0, 256), 256, 0, stream>>>(keep, pos, N0, perm1, map1);
    pool_apply_kernel<128><<<g((long long)K1 * 32, 256), 256, 0, stream>>>(x1f, score, perm1, xp1f, xp1Hi, xp1Lo, K1);

    // ---- CSR graph1 (filter CSR graph0 through map1) ----
    deg_filter_kernel<<<g(N0, 256), 256, 0, stream>>>(rp0, cols0, map1, N0, deg);
    exclusive_scan_kernel<<<1, 1024, 0, stream>>>(deg, rp1, cursor, K1);
    csr_filter_fill_kernel<<<g(N0, 256), 256, 0, stream>>>(rp0, cols0, map1, N0, rp1, cols1);

    // ---- Layer 2 ----
    aggregate_kernel<128><<<g(K1, 8), 256, 0, stream>>>(rp1, cols1, xp1f, aggHi, aggLo, K1);
    linear_mfma_kernel<128, 64><<<g(K1, 64), 256, 0, stream>>>(K1, aggHi, aggLo, w2rHi, w2rLo,
                                                               xp1Hi, xp1Lo, w2tHi, w2tLo, b2f, x2f);

    // ---- Pool 2 (radix-select top-K2) ----
    score_kernel<64><<<g(K1, 4), 256, 0, stream>>>(x2f, p2f, K1, score, keys);
    for (int pass = 0; pass < 4; ++pass) {
        radix_hist_kernel<<<64, 256, 0, stream>>>(keys, K1, hist, ctl, pass);
        radix_select_kernel<<<1, 1024, 0, stream>>>(hist, ctl, K2, pass);
    }
    mark_keep_kernel<<<g(K1, 256), 256, 0, stream>>>(keys, K1, ctl, keep);
    exclusive_scan_kernel<<<1, 1024, 0, stream>>>(keep, pos, cursor, K1);
    finalize_map_kernel<<<g(K1, 256), 256, 0, stream>>>(keep, pos, K1, perm2, map2);
    pool_apply_kernel<64><<<g((long long)K2 * 16, 256), 256, 0, stream>>>(x2f, score, perm2, xp2f, xp2Hi, xp2Lo, K2);

    // ---- CSR graph2 (filter CSR graph1 through map2) ----
    deg_filter_kernel<<<g(K1, 256), 256, 0, stream>>>(rp1, cols1, map2, K1, deg);
    exclusive_scan_kernel<<<1, 1024, 0, stream>>>(deg, rp2, cursor, K2);
    csr_filter_fill_kernel<<<g(K1, 256), 256, 0, stream>>>(rp1, cols1, map2, K1, rp2, cols2);

    // ---- Layer 3 ----
    aggregate_kernel<64><<<g(K2, 16), 256, 0, stream>>>(rp2, cols2, xp2f, aggHi, aggLo, K2);
    linear_mfma_kernel<64, 64><<<g(K2, 64), 256, 0, stream>>>(K2, aggHi, aggLo, w3rHi, w3rLo,
                                                              xp2Hi, xp2Lo, w3tHi, w3tLo, b3f, x3f);

    // ---- Unpool 1 (in-place on x2f) ----
    unpool_add_kernel<64><<<g((long long)K1 * 16, 256), 256, 0, stream>>>(x2f, x3f, map2, u1f, u1Hi, u1Lo, K1);

    // ---- Layer 4 ----
    aggregate_kernel<64><<<g(K1, 16), 256, 0, stream>>>(rp1, cols1, u1f, aggHi, aggLo, K1);
    linear_mfma_kernel<64, 128><<<g(K1, 64), 256, 0, stream>>>(K1, aggHi, aggLo, w4rHi, w4rLo,
                                                               u1Hi, u1Lo, w4tHi, w4tLo, b4f, x4f);

    // ---- Unpool 2 (f32 in-place on x1f) ----
    unpool_add_kernel<128><<<g((long long)N0 * 32, 256), 256, 0, stream>>>(x1f, x4f, map1, x1f, u2Hi, u2Lo, N0);

    // ---- Layer 5 ----
    aggregate_kernel<128><<<g(N0, 8), 256, 0, stream>>>(rp0, cols0, x1f, aggHi, aggLo, N0);
    linear_mfma_kernel<128, 128><<<g(N0, 64), 256, 0, stream>>>(N0, aggHi, aggLo, w5rHi, w5rLo,
                                                                u2Hi, u2Lo, w5tHi, w5tLo, b5f, x5f);

    // ---- Head ----
    head_kernel<<<g(N0, 4), 256, 0, stream>>>(x5f, lwf, lbf, d_out, N0, flag);
}

// Round 4
// 1122.291 us; speedup vs baseline: 1.4148x; 1.4148x over previous
//
#include <hip/hip_runtime.h>
#include <hip/hip_bf16.h>
#include <math.h>

#define N0 50000
#define E0 1600000
#define K1 40000
#define K2 32000
#define FEAT 128
#define HID 128
#define EMB 64
#define NCLS 10

#define RADIX_BINS 4096   // 12-bit digits, 4 passes over the 48-bit key

// CSR bucketed build: 128 dsts per bucket
#define NB 391            // ceil(50000 / 128)
#define PB_CH 8192        // edges per partition block
#define BCAP 5120         // LDS staging capacity (avg bucket = 4096, +16 sigma)

#define SCHUNK 2048       // hierarchical scan: elements per block (256 thr x 8)

typedef __bf16 v8bf __attribute__((ext_vector_type(8)));
typedef __bf16 v4bf __attribute__((ext_vector_type(4)));
typedef float  v4f  __attribute__((ext_vector_type(4)));

static __device__ __forceinline__ unsigned f2key(float f) {
    unsigned u = __float_as_uint(f);
    return (u & 0x80000000u) ? ~u : (u | 0x80000000u);
}

// ---------- dtype detection ----------
__global__ void detect_dtype_kernel(const unsigned* __restrict__ w, int n, int* __restrict__ flag) {
    __shared__ int tot;
    if (threadIdx.x == 0) tot = 0;
    __syncthreads();
    int cnt = 0;
    for (int i = threadIdx.x; i < n; i += 256) {
        unsigned lo = w[i] & 0xFFFFu;
        unsigned e = (lo >> 7) & 0xFFu;
        cnt += (e >= 143);
    }
    atomicAdd(&tot, cnt);
    __syncthreads();
    if (threadIdx.x == 0) flag[0] = (tot > n / 8) ? 1 : 0;  // 1 = f32, 0 = bf16
}

static __device__ __forceinline__ float load_as_f32(const void* in, long long i, int isF32) {
    if (isF32) return ((const float*)in)[i];
    unsigned short h = ((const unsigned short*)in)[i];
    return __uint_as_float(((unsigned)h) << 16);
}

// x: one pass -> f32 + (hi,lo)
__global__ void x_convert_kernel(const void* __restrict__ in, float* __restrict__ xf,
                                 __bf16* __restrict__ hi, __bf16* __restrict__ lo, int n,
                                 const int* __restrict__ flag) {
    int i = blockIdx.x * 256 + threadIdx.x;
    if (i >= n) return;
    float v = load_as_f32(in, i, *flag);
    __bf16 h = (__bf16)v;
    xf[i] = v; hi[i] = h; lo[i] = (__bf16)(v - (float)h);
}

// batched weight splits (10 tensors in one launch)
struct SplitJob { const void* src; __bf16* hi; __bf16* lo; int n; };
struct SplitJobs { SplitJob j[10]; };
__global__ void split_all_kernel(SplitJobs jobs, const int* __restrict__ flag) {
    SplitJob jb = jobs.j[blockIdx.y];
    int i = blockIdx.x * 256 + threadIdx.x;
    if (i >= jb.n) return;
    float v = load_as_f32(jb.src, i, *flag);
    __bf16 h = (__bf16)v;
    jb.hi[i] = h; jb.lo[i] = (__bf16)(v - (float)h);
}

// batched small f32 conversions (9 tensors, one block each)
struct F32Job { const void* src; float* dst; int n; };
struct F32Jobs { F32Job j[9]; };
__global__ void f32_all_kernel(F32Jobs jobs, const int* __restrict__ flag) {
    F32Job jb = jobs.j[blockIdx.x];
    for (int i = threadIdx.x; i < jb.n; i += 256) jb.dst[i] = load_as_f32(jb.src, i, *flag);
}

// ---------- CSR graph0: degree count ----------
__global__ void deg_count_kernel(const int* __restrict__ dst, int E, int* __restrict__ deg) {
    int e = blockIdx.x * 256 + threadIdx.x;
    if (e >= E) return;
    atomicAdd(&deg[dst[e]], 1);
}

// ---------- hierarchical exclusive scan (3 tiny parallel launches) ----------
// Old single-block scan was latency-bound at ~126us/dispatch x5 (0.15% occupancy).
__global__ void scan_reduce_kernel(const int* __restrict__ deg, int M, int* __restrict__ btot) {
    int t = threadIdx.x;
    int idx = blockIdx.x * SCHUNK + t * 8;
    int s = 0;
    if (idx + 8 <= M) {
        int4 a = *(const int4*)(deg + idx);
        int4 b = *(const int4*)(deg + idx + 4);
        s = a.x + a.y + a.z + a.w + b.x + b.y + b.z + b.w;
    } else {
        for (int k = 0; k < 8; ++k) if (idx + k < M) s += deg[idx + k];
    }
    for (int off = 32; off >= 1; off >>= 1) s += __shfl_xor(s, off, 64);
    __shared__ int ws[4];
    if ((t & 63) == 0) ws[t >> 6] = s;
    __syncthreads();
    if (t == 0) btot[blockIdx.x] = ws[0] + ws[1] + ws[2] + ws[3];
}

// one wave: exclusive scan of <=64 block totals; grand total -> totPtr[0]
__global__ void scan_offsets_kernel(const int* __restrict__ btot, int nb,
                                    int* __restrict__ boff, int* __restrict__ totPtr) {
    int t = threadIdx.x;
    int v = (t < nb) ? btot[t] : 0;
    int incl = v;
    for (int off = 1; off < 64; off <<= 1) {
        int u = __shfl_up(incl, off, 64);
        if (t >= off) incl += u;
    }
    if (t < nb) boff[t] = incl - v;
    if (t == 63 && totPtr) totPtr[0] = incl;
}

__global__ void scan_apply_kernel(const int* __restrict__ deg, int M, const int* __restrict__ boff,
                                  int* __restrict__ rowptr, int* __restrict__ cursor) {
    int t = threadIdx.x;
    int lane = t & 63, wave = t >> 6;
    int idx = blockIdx.x * SCHUNK + t * 8;
    int v[8];
#pragma unroll
    for (int k = 0; k < 8; ++k) v[k] = (idx + k < M) ? deg[idx + k] : 0;
    int s = 0;
#pragma unroll
    for (int k = 0; k < 8; ++k) { int tmp = v[k]; v[k] = s; s += tmp; }  // thread-local exclusive
    int incl = s;
    for (int off = 1; off < 64; off <<= 1) {
        int u = __shfl_up(incl, off, 64);
        if (lane >= off) incl += u;
    }
    int texcl = incl - s;
    __shared__ int ws[4];
    if (lane == 63) ws[wave] = incl;
    __syncthreads();
    int woff = 0;
    for (int w = 0; w < 4; ++w) if (w < wave) woff += ws[w];
    int off0 = boff[blockIdx.x] + woff + texcl;
#pragma unroll
    for (int k = 0; k < 8; ++k) {
        int j = idx + k;
        if (j < M) {
            int val = off0 + v[k];
            rowptr[j] = val;
            if (cursor) cursor[j] = val;
        }
    }
}

// ---------- CSR graph0: bucketed two-pass fill (write line-density fix) ----------
__global__ void bcur_init_kernel(const int* __restrict__ rp, int* __restrict__ bcur) {
    int b = blockIdx.x * 256 + threadIdx.x;
    if (b < NB) bcur[b] = rp[b << 7];
}

__global__ void edge_partition_kernel(const int* __restrict__ src, const int* __restrict__ dst, int E,
                                      int* __restrict__ bcur, unsigned* __restrict__ pairBuf) {
    __shared__ int cnt[NB];
    __shared__ int bas[NB];
    for (int b = threadIdx.x; b < NB; b += 256) cnt[b] = 0;
    __syncthreads();
    int e0 = blockIdx.x * PB_CH;
    int e1 = E < e0 + PB_CH ? E : e0 + PB_CH;
    for (int e = e0 + threadIdx.x; e < e1; e += 256)
        atomicAdd(&cnt[dst[e] >> 7], 1);
    __syncthreads();
    for (int b = threadIdx.x; b < NB; b += 256) {
        int c = cnt[b];
        bas[b] = c ? atomicAdd(&bcur[b], c) : 0;
        cnt[b] = 0;
    }
    __syncthreads();
    for (int e = e0 + threadIdx.x; e < e1; e += 256) {
        int s = src[e], d = dst[e];
        int b = d >> 7;
        int r = atomicAdd(&cnt[b], 1);
        pairBuf[bas[b] + r] = ((unsigned)(d & 127) << 16) | (unsigned)s;  // both < 65536
    }
}

__global__ void bucket_csr_fill_kernel(const unsigned* __restrict__ pairBuf, const int* __restrict__ rp,
                                       int Mrows, int* __restrict__ cols, int* __restrict__ gcursor) {
    int b = blockIdx.x;
    int d0 = b << 7;
    int d1 = d0 + 128; if (d1 > Mrows) d1 = Mrows;
    int segBase = rp[d0], segEnd = rp[d1];
    int size = segEnd - segBase;
    __shared__ int cur[128];
    __shared__ int stage[BCAP];
    if (size <= BCAP) {
        for (int j = threadIdx.x; j < d1 - d0; j += 256) cur[j] = rp[d0 + j] - segBase;
        __syncthreads();
        for (int t = threadIdx.x; t < size; t += 256) {
            unsigned p = pairBuf[segBase + t];
            int pos = atomicAdd(&cur[p >> 16], 1);
            stage[pos] = (int)(p & 0xFFFFu);
        }
        __syncthreads();
        for (int t = threadIdx.x; t < size; t += 256) cols[segBase + t] = stage[t];
    } else {  // statistically unreachable; correctness fallback
        for (int t = threadIdx.x; t < size; t += 256) {
            unsigned p = pairBuf[segBase + t];
            int pos = atomicAdd(&gcursor[d0 + (int)(p >> 16)], 1);
            cols[pos] = (int)(p & 0xFFFFu);
        }
    }
}

// ---------- CSR graph k+1 from CSR k (filter through monotonic mapping) ----------
__global__ void deg_filter_kernel(const int* __restrict__ rowptr, const int* __restrict__ cols,
                                  const int* __restrict__ map, int Mold, int* __restrict__ deg) {
    int d = blockIdx.x * 256 + threadIdx.x;
    if (d >= Mold) return;
    int nd = map[d];
    if (nd < 0) return;
    int b = rowptr[d], e = rowptr[d + 1];
    int c = 0;
    for (int j = b; j < e; ++j) c += (map[cols[j]] >= 0);
    deg[nd] = c;
}

__global__ void csr_filter_fill_kernel(const int* __restrict__ rowptr, const int* __restrict__ cols,
                                       const int* __restrict__ map, int Mold,
                                       const int* __restrict__ newrp, int* __restrict__ ncols) {
    int d = blockIdx.x * 256 + threadIdx.x;
    if (d >= Mold) return;
    int nd = map[d];
    if (nd < 0) return;
    int w = newrp[nd];
    int b = rowptr[d], e = rowptr[d + 1];
    for (int j = b; j < e; ++j) {
        int ns = map[cols[j]];
        if (ns >= 0) ncols[w++] = ns;
    }
}

// ---------- gather aggregation: f32 gather/accumulate, hi/lo bf16 out ----------
template<int C>
__global__ void aggregate_kernel(const int* __restrict__ rowptr, const int* __restrict__ cols,
                                 const float* __restrict__ x, __bf16* __restrict__ aggHi,
                                 __bf16* __restrict__ aggLo, int M) {
    const int CH = C / 4;
    const int NPB = 256 / CH;
    int n = blockIdx.x * NPB + threadIdx.x / CH;
    int c4 = threadIdx.x % CH;
    if (n >= M) return;
    int b = rowptr[n], e = rowptr[n + 1];
    float4 s = {0.f, 0.f, 0.f, 0.f};
    for (int j = b; j < e; ++j) {
        int src = cols[j];
        float4 v = ((const float4*)(x + (size_t)src * C))[c4];
        s.x += v.x; s.y += v.y; s.z += v.z; s.w += v.w;
    }
    v4bf h, l;
    h[0] = (__bf16)s.x; l[0] = (__bf16)(s.x - (float)h[0]);
    h[1] = (__bf16)s.y; l[1] = (__bf16)(s.y - (float)h[1]);
    h[2] = (__bf16)s.z; l[2] = (__bf16)(s.z - (float)h[2]);
    h[3] = (__bf16)s.w; l[3] = (__bf16)(s.w - (float)h[3]);
    *(v4bf*)(aggHi + (size_t)n * C + c4 * 4) = h;
    *(v4bf*)(aggLo + (size_t)n * C + c4 * 4) = l;
}

// ---------- split-precision MFMA dual linear + bias + relu ----------
template<int Cin, int Cout>
__global__ void linear_mfma_kernel(int M,
                                   const __bf16* __restrict__ Ahi, const __bf16* __restrict__ Alo,
                                   const __bf16* __restrict__ WaHi, const __bf16* __restrict__ WaLo,
                                   const __bf16* __restrict__ Bhi, const __bf16* __restrict__ Blo,
                                   const __bf16* __restrict__ WbHi, const __bf16* __restrict__ WbLo,
                                   const float* __restrict__ bias, float* __restrict__ outF) {
    constexpr int NG = Cout / 16;
    int wave = threadIdx.x >> 6;
    int lane = threadIdx.x & 63;
    int m = lane & 15, quad = lane >> 4;
    int row0 = blockIdx.x * 64 + wave * 16;
    int ra = row0 + m; if (ra > M - 1) ra = M - 1;

    v4f acc[NG];
#pragma unroll
    for (int g = 0; g < NG; ++g) acc[g] = (v4f){0.f, 0.f, 0.f, 0.f};

#pragma unroll
    for (int ks = 0; ks < Cin / 32; ++ks) {
        size_t aoff = (size_t)ra * Cin + ks * 32 + quad * 8;
        v8bf ah = *(const v8bf*)(Ahi + aoff);
        v8bf al = *(const v8bf*)(Alo + aoff);
#pragma unroll
        for (int g = 0; g < NG; ++g) {
            size_t woff = (size_t)(g * 16 + m) * Cin + ks * 32 + quad * 8;
            v8bf bh = *(const v8bf*)(WaHi + woff);
            v8bf bl = *(const v8bf*)(WaLo + woff);
            acc[g] = __builtin_amdgcn_mfma_f32_16x16x32_bf16(ah, bh, acc[g], 0, 0, 0);
            acc[g] = __builtin_amdgcn_mfma_f32_16x16x32_bf16(ah, bl, acc[g], 0, 0, 0);
            acc[g] = __builtin_amdgcn_mfma_f32_16x16x32_bf16(al, bh, acc[g], 0, 0, 0);
        }
    }
#pragma unroll
    for (int ks = 0; ks < Cin / 32; ++ks) {
        size_t aoff = (size_t)ra * Cin + ks * 32 + quad * 8;
        v8bf ah = *(const v8bf*)(Bhi + aoff);
        v8bf al = *(const v8bf*)(Blo + aoff);
#pragma unroll
        for (int g = 0; g < NG; ++g) {
            size_t woff = (size_t)(g * 16 + m) * Cin + ks * 32 + quad * 8;
            v8bf bh = *(const v8bf*)(WbHi + woff);
            v8bf bl = *(const v8bf*)(WbLo + woff);
            acc[g] = __builtin_amdgcn_mfma_f32_16x16x32_bf16(ah, bh, acc[g], 0, 0, 0);
            acc[g] = __builtin_amdgcn_mfma_f32_16x16x32_bf16(ah, bl, acc[g], 0, 0, 0);
            acc[g] = __builtin_amdgcn_mfma_f32_16x16x32_bf16(al, bh, acc[g], 0, 0, 0);
        }
    }

    // C/D layout: col = lane&15, row = quad*4 + reg
#pragma unroll
    for (int g = 0; g < NG; ++g) {
        int col = g * 16 + m;
        float bv = bias[col];
#pragma unroll
        for (int r = 0; r < 4; ++r) {
            int row = row0 + quad * 4 + r;
            if (row < M) outF[(size_t)row * Cout + col] = fmaxf(acc[g][r] + bv, 0.f);
        }
    }
}

// ---------- pooling score (fused 48-bit selection key build) ----------
// key = (f2key(score) << 16) | (~i & 0xFFFF)   -- valid since N <= 65536;
// preserves exact smaller-index-first tie-break of jax.lax.top_k.
template<int C>
__global__ void score_kernel(const float* __restrict__ xin, const float* __restrict__ w,
                             int M, float* __restrict__ score, unsigned long long* __restrict__ keys) {
    int row = blockIdx.x * 4 + (threadIdx.x >> 6);
    int lane = threadIdx.x & 63;
    if (row >= M) return;
    float p = 0.f, q = 0.f;
#pragma unroll
    for (int c = lane; c < C; c += 64) {
        float wc = w[c];
        float xc = xin[(size_t)row * C + c];
        p += xc * wc; q += wc * wc;
    }
#pragma unroll
    for (int off = 32; off >= 1; off >>= 1) {
        p += __shfl_xor(p, off, 64);
        q += __shfl_xor(q, off, 64);
    }
    if (lane == 0) {
        float arg = p / sqrtf(q);
        float sc = (float)tanh((double)arg);
        score[row] = sc;
        keys[row] = ((unsigned long long)f2key(sc) << 16) |
                    (unsigned long long)(0xFFFFu ^ (unsigned)row);
    }
}

// ---------- radix-select top-K threshold (4 passes of 12-bit digits on 48-bit keys) ----------
// LDS-privatized histogram (tanh clusters scores; global same-address atomics serialize).
struct SelCtl { unsigned long long prefix; int kRem; int counter; };

__global__ void radix_hist_kernel(const unsigned long long* __restrict__ keys, int N,
                                  int* __restrict__ hist, const SelCtl* __restrict__ ctl, int pass) {
    __shared__ int lh[RADIX_BINS];
    for (int b = threadIdx.x; b < RADIX_BINS; b += 256) lh[b] = 0;
    __syncthreads();
    int shift = 36 - 12 * pass;                 // pass0: bits[36:48) ... pass3: bits[0:12)
    unsigned long long pref = (pass > 0) ? ctl->prefix : 0ull;
    for (int i = blockIdx.x * 256 + threadIdx.x; i < N; i += gridDim.x * 256) {
        unsigned long long key = keys[i];
        if (pass > 0 && (key >> (shift + 12)) != pref) continue;
        atomicAdd(&lh[(int)((key >> shift) & 0xFFFull)], 1);
    }
    __syncthreads();
    for (int b = threadIdx.x; b < RADIX_BINS; b += 256) {
        int c = lh[b];
        if (c) atomicAdd(&hist[b], c);          // <=gridDim adds per address
    }
}

// single block, 1024 threads (4 bins each); finds digit containing the kRem-th
// largest key, updates ctl, and re-zeros the histogram for the next pass.
__global__ void radix_select_kernel(int* __restrict__ hist, SelCtl* __restrict__ ctl,
                                    int K, int pass) {
    __shared__ int part[1024];
    int t = threadIdx.x;
    int kRem = (pass == 0) ? K : ctl->kRem;
    unsigned long long oldPrefix = (pass == 0) ? 0ull : ctl->prefix;
    int base = t * 4;
    int h0 = hist[base], h1 = hist[base + 1], h2 = hist[base + 2], h3 = hist[base + 3];
    int tot = h0 + h1 + h2 + h3;
    part[t] = tot;
    __syncthreads();
    // inclusive suffix sum: part[t] = sum_{t' >= t} tot(t')
    for (int off = 1; off < 1024; off <<= 1) {
        int v = (t + off < 1024) ? part[t + off] : 0;
        __syncthreads();
        part[t] += v;
        __syncthreads();
    }
    int sExcl = part[t] - tot;                  // keys with digit in a strictly higher chunk
    if (sExcl < kRem && kRem <= sExcl + tot) {  // crossing chunk (unique; tot>0 here)
        int c = sExcl;
        int hv[4] = {h0, h1, h2, h3};
        for (int k = 3; k >= 0; --k) {
            int h = hv[k];
            if (c + h >= kRem) {
                ctl->prefix = (oldPrefix << 12) | (unsigned long long)(base + k);
                ctl->kRem = kRem - c;
                ctl->counter = 0;
                break;
            }
            c += h;
        }
    }
    // re-zero for the next histogram pass
    hist[base] = 0; hist[base + 1] = 0; hist[base + 2] = 0; hist[base + 3] = 0;
}

// ---------- monotonic keep/compact (makes CSR-filter writes sequential) ----------
__global__ void mark_keep_kernel(const unsigned long long* __restrict__ keys, int N,
                                 const SelCtl* __restrict__ ctl, int* __restrict__ keep) {
    int i = blockIdx.x * 256 + threadIdx.x;
    if (i < N) keep[i] = (keys[i] >= ctl->prefix) ? 1 : 0;
}

__global__ void finalize_map_kernel(const int* __restrict__ keep, const int* __restrict__ pos,
                                    int N, int* __restrict__ perm, int* __restrict__ mapping) {
    int i = blockIdx.x * 256 + threadIdx.x;
    if (i >= N) return;
    if (keep[i]) { int r = pos[i]; perm[r] = i; mapping[i] = r; }
    else mapping[i] = -1;
}

// xp[j] = x[perm[j]] * score[perm[j]]  -> f32 + (hi,lo)
template<int C>
__global__ void pool_apply_kernel(const float* __restrict__ xin, const float* __restrict__ score,
                                  const int* __restrict__ perm, float* __restrict__ xpF,
                                  __bf16* __restrict__ xpHi, __bf16* __restrict__ xpLo, int K) {
    const int CH = C / 4;
    int tid = blockIdx.x * 256 + threadIdx.x;
    int j = tid / CH, c4 = tid % CH;
    if (j >= K) return;
    int src = perm[j];
    float s = score[src];
    float4 v = ((const float4*)(xin + (size_t)src * C))[c4];
    v.x *= s; v.y *= s; v.z *= s; v.w *= s;
    ((float4*)(xpF + (size_t)j * C))[c4] = v;
    v4bf h, l;
    h[0] = (__bf16)v.x; l[0] = (__bf16)(v.x - (float)h[0]);
    h[1] = (__bf16)v.y; l[1] = (__bf16)(v.y - (float)h[1]);
    h[2] = (__bf16)v.z; l[2] = (__bf16)(v.z - (float)h[2]);
    h[3] = (__bf16)v.w; l[3] = (__bf16)(v.w - (float)h[3]);
    *(v4bf*)(xpHi + (size_t)j * C + c4 * 4) = h;
    *(v4bf*)(xpLo + (size_t)j * C + c4 * 4) = l;
}

// u[j] = base[j] + (mapping[j]>=0 ? deep[mapping[j]] : 0)  -> f32 + (hi,lo); uF may alias base
template<int C>
__global__ void unpool_add_kernel(const float* __restrict__ base, const float* __restrict__ deep,
                                  const int* __restrict__ mapping, float* __restrict__ uF,
                                  __bf16* __restrict__ uHi, __bf16* __restrict__ uLo, int M) {
    const int CH = C / 4;
    int tid = blockIdx.x * 256 + threadIdx.x;
    int j = tid / CH, c4 = tid % CH;
    if (j >= M) return;
    float4 v = ((const float4*)(base + (size_t)j * C))[c4];
    int m = mapping[j];
    if (m >= 0) {
        float4 d = ((const float4*)(deep + (size_t)m * C))[c4];
        v.x += d.x; v.y += d.y; v.z += d.z; v.w += d.w;
    }
    ((float4*)(uF + (size_t)j * C))[c4] = v;
    v4bf h, l;
    h[0] = (__bf16)v.x; l[0] = (__bf16)(v.x - (float)h[0]);
    h[1] = (__bf16)v.y; l[1] = (__bf16)(v.y - (float)h[1]);
    h[2] = (__bf16)v.z; l[2] = (__bf16)(v.z - (float)h[2]);
    h[3] = (__bf16)v.w; l[3] = (__bf16)(v.w - (float)h[3]);
    *(v4bf*)(uHi + (size_t)j * C + c4 * 4) = h;
    *(v4bf*)(uLo + (size_t)j * C + c4 * 4) = l;
}

__global__ void head_kernel(const float* __restrict__ x5, const float* __restrict__ lw,
                            const float* __restrict__ lb, void* __restrict__ out, int M,
                            const int* __restrict__ flag) {
    int row = blockIdx.x * 4 + (threadIdx.x >> 6);
    int lane = threadIdx.x & 63;
    if (row >= M) return;
    float a0 = x5[(size_t)row * 128 + lane];
    float a1 = x5[(size_t)row * 128 + 64 + lane];
    float d[NCLS];
#pragma unroll
    for (int o = 0; o < NCLS; ++o) {
        float p = a0 * lw[o * 128 + lane] + a1 * lw[o * 128 + 64 + lane];
#pragma unroll
        for (int off = 32; off >= 1; off >>= 1) p += __shfl_xor(p, off, 64);
        d[o] = p + lb[o];
    }
    float mx = d[0];
#pragma unroll
    for (int o = 1; o < NCLS; ++o) mx = fmaxf(mx, d[o]);
    float s = 0.f;
#pragma unroll
    for (int o = 0; o < NCLS; ++o) s += expf(d[o] - mx);
    float lse = mx + logf(s);
    if (lane < NCLS) {
        float v = d[0];
#pragma unroll
        for (int o = 1; o < NCLS; ++o) if (lane == o) v = d[o];
        float r = v - lse;
        if (*flag) ((float*)out)[(size_t)row * NCLS + lane] = r;
        else ((__hip_bfloat16*)out)[(size_t)row * NCLS + lane] = __float2bfloat16(r);
    }
}

extern "C" void kernel_launch(void* const* d_in, const int* in_sizes, int n_in,
                              void* d_out, int out_size, void* d_ws, size_t ws_size,
                              hipStream_t stream) {
    const void* x_raw   = d_in[0];
    const int*  ei      = (const int*)d_in[1];
    const void* w1_rel  = d_in[2];
    const void* w1_root = d_in[3];
    const void* b1      = d_in[4];
    const void* p1w     = d_in[5];
    const void* w2_rel  = d_in[6];
    const void* w2_root = d_in[7];
    const void* b2      = d_in[8];
    const void* p2w     = d_in[9];
    const void* w3_rel  = d_in[10];
    const void* w3_root = d_in[11];
    const void* b3      = d_in[12];
    const void* w4_rel  = d_in[13];
    const void* w4_root = d_in[14];
    const void* b4      = d_in[15];
    const void* w5_rel  = d_in[16];
    const void* w5_root = d_in[17];
    const void* b5      = d_in[18];
    const void* lw      = d_in[19];
    const void* lb      = d_in[20];

    char* base = (char*)d_ws;
    size_t off = 0;
    auto alloc = [&](size_t bytes) -> void* {
        void* p = base + off;
        off = (off + bytes + 255) & ~(size_t)255;
        return p;
    };
    int* flag = (int*)alloc(256);
    __bf16* w1rHi = (__bf16*)alloc(HID * FEAT * 2); __bf16* w1rLo = (__bf16*)alloc(HID * FEAT * 2);
    __bf16* w1tHi = (__bf16*)alloc(HID * FEAT * 2); __bf16* w1tLo = (__bf16*)alloc(HID * FEAT * 2);
    __bf16* w2rHi = (__bf16*)alloc(EMB * HID * 2);  __bf16* w2rLo = (__bf16*)alloc(EMB * HID * 2);
    __bf16* w2tHi = (__bf16*)alloc(EMB * HID * 2);  __bf16* w2tLo = (__bf16*)alloc(EMB * HID * 2);
    __bf16* w3rHi = (__bf16*)alloc(EMB * EMB * 2);  __bf16* w3rLo = (__bf16*)alloc(EMB * EMB * 2);
    __bf16* w3tHi = (__bf16*)alloc(EMB * EMB * 2);  __bf16* w3tLo = (__bf16*)alloc(EMB * EMB * 2);
    __bf16* w4rHi = (__bf16*)alloc(HID * EMB * 2);  __bf16* w4rLo = (__bf16*)alloc(HID * EMB * 2);
    __bf16* w4tHi = (__bf16*)alloc(HID * EMB * 2);  __bf16* w4tLo = (__bf16*)alloc(HID * EMB * 2);
    __bf16* w5rHi = (__bf16*)alloc(FEAT * HID * 2); __bf16* w5rLo = (__bf16*)alloc(FEAT * HID * 2);
    __bf16* w5tHi = (__bf16*)alloc(FEAT * HID * 2); __bf16* w5tLo = (__bf16*)alloc(FEAT * HID * 2);
    float* b1f = (float*)alloc(HID * 4);
    float* b2f = (float*)alloc(EMB * 4);
    float* b3f = (float*)alloc(EMB * 4);
    float* b4f = (float*)alloc(HID * 4);
    float* b5f = (float*)alloc(FEAT * 4);
    float* p1f = (float*)alloc(HID * 4);
    float* p2f = (float*)alloc(EMB * 4);
    float* lwf = (float*)alloc(NCLS * FEAT * 4);
    float* lbf = (float*)alloc(NCLS * 4);
    float* score = (float*)alloc((size_t)N0 * 4);
    unsigned long long* keys = (unsigned long long*)alloc((size_t)N0 * 8);
    int* hist = (int*)alloc((size_t)RADIX_BINS * 4);
    SelCtl* ctl = (SelCtl*)alloc(256);
    int* btot = (int*)alloc(64 * 4);
    int* boff = (int*)alloc(64 * 4);
    int* perm1 = (int*)alloc((size_t)K1 * 4);
    int* map1  = (int*)alloc((size_t)N0 * 4);
    int* perm2 = (int*)alloc((size_t)K2 * 4);
    int* map2  = (int*)alloc((size_t)K1 * 4);
    int* keep  = (int*)alloc((size_t)(N0 + 1) * 4);
    int* pos   = (int*)alloc((size_t)(N0 + 1) * 4);
    int* deg   = (int*)alloc((size_t)(N0 + 1) * 4);
    int* cursor= (int*)alloc((size_t)(N0 + 1) * 4);
    int* rp0   = (int*)alloc((size_t)(N0 + 1) * 4);
    int* rp1   = (int*)alloc((size_t)(K1 + 1) * 4);
    int* rp2   = (int*)alloc((size_t)(K2 + 1) * 4);
    int* bcur  = (int*)alloc((size_t)NB * 4);
    int* cols0 = (int*)alloc((size_t)E0 * 4);
    int* cols1 = (int*)alloc((size_t)E0 * 4);
    int* cols2 = (int*)alloc((size_t)E0 * 4);
    unsigned* pairBuf = (unsigned*)alloc((size_t)E0 * 4);
    // aliased activation arenas
    char*   arenaX  = (char*)alloc((size_t)N0 * 128 * 4);   // xf -> xp1f -> {xp2f,x3f} -> x4f -> x5f
    __bf16* arenaHi = (__bf16*)alloc((size_t)N0 * 128 * 2);
    __bf16* arenaLo = (__bf16*)alloc((size_t)N0 * 128 * 2);
    __bf16* aggHi   = (__bf16*)alloc((size_t)N0 * 128 * 2);
    __bf16* aggLo   = (__bf16*)alloc((size_t)N0 * 128 * 2);
    float*  x1f     = (float*)alloc((size_t)N0 * 128 * 4);  // persists; becomes u2 f32 in-place
    float*  x2f     = (float*)alloc((size_t)K1 * 64 * 4);   // persists; becomes u1 f32 in-place

    float* xf   = (float*)arenaX;
    float* xp1f = (float*)arenaX;
    float* xp2f = (float*)arenaX;
    float* x3f  = (float*)(arenaX + 8388608);
    float* x4f  = (float*)arenaX;
    float* x5f  = (float*)arenaX;
    __bf16 *xHi = arenaHi,  *xLo = arenaLo;
    __bf16 *xp1Hi = arenaHi, *xp1Lo = arenaLo;
    __bf16 *xp2Hi = arenaHi, *xp2Lo = arenaLo;
    __bf16 *u1Hi = arenaHi,  *u1Lo = arenaLo;
    __bf16 *u2Hi = arenaHi,  *u2Lo = arenaLo;
    float* u1f = x2f;

    const int* src0 = ei;
    const int* dst0 = ei + E0;

    auto g = [](long long n, int b) -> unsigned { return (unsigned)((n + b - 1) / b); };

    // hierarchical exclusive scan: deg[M] -> rowp[0..M] (+optional cursor copy)
    auto run_scan = [&](const int* degp, int M, int* rowp, int* curp) {
        int nb = (M + SCHUNK - 1) / SCHUNK;
        scan_reduce_kernel<<<nb, 256, 0, stream>>>(degp, M, btot);
        scan_offsets_kernel<<<1, 64, 0, stream>>>(btot, nb, boff, rowp + M);
        scan_apply_kernel<<<nb, 256, 0, stream>>>(degp, M, boff, rowp, curp);
    };

    // ---- dtype detect + fused conversions ----
    detect_dtype_kernel<<<1, 256, 0, stream>>>((const unsigned*)x_raw, 4096, flag);
    hipMemsetAsync(hist, 0, (size_t)RADIX_BINS * 4, stream);  // selects re-zero after each pass
    x_convert_kernel<<<g((long long)N0 * FEAT, 256), 256, 0, stream>>>(x_raw, xf, xHi, xLo, N0 * FEAT, flag);
    {
        SplitJobs sj;
        sj.j[0] = {w1_rel,  w1rHi, w1rLo, HID * FEAT};
        sj.j[1] = {w1_root, w1tHi, w1tLo, HID * FEAT};
        sj.j[2] = {w2_rel,  w2rHi, w2rLo, EMB * HID};
        sj.j[3] = {w2_root, w2tHi, w2tLo, EMB * HID};
        sj.j[4] = {w3_rel,  w3rHi, w3rLo, EMB * EMB};
        sj.j[5] = {w3_root, w3tHi, w3tLo, EMB * EMB};
        sj.j[6] = {w4_rel,  w4rHi, w4rLo, HID * EMB};
        sj.j[7] = {w4_root, w4tHi, w4tLo, HID * EMB};
        sj.j[8] = {w5_rel,  w5rHi, w5rLo, FEAT * HID};
        sj.j[9] = {w5_root, w5tHi, w5tLo, FEAT * HID};
        dim3 grid(g(HID * FEAT, 256), 10);
        split_all_kernel<<<grid, 256, 0, stream>>>(sj, flag);
    }
    {
        F32Jobs fj;
        fj.j[0] = {b1, b1f, HID};
        fj.j[1] = {b2, b2f, EMB};
        fj.j[2] = {b3, b3f, EMB};
        fj.j[3] = {b4, b4f, HID};
        fj.j[4] = {b5, b5f, FEAT};
        fj.j[5] = {p1w, p1f, HID};
        fj.j[6] = {p2w, p2f, EMB};
        fj.j[7] = {lw, lwf, NCLS * FEAT};
        fj.j[8] = {lb, lbf, NCLS};
        f32_all_kernel<<<9, 256, 0, stream>>>(fj, flag);
    }

    // ---- CSR graph0 (bucketed two-pass build) ----
    hipMemsetAsync(deg, 0, (size_t)N0 * 4, stream);
    deg_count_kernel<<<g(E0, 256), 256, 0, stream>>>(dst0, E0, deg);
    run_scan(deg, N0, rp0, cursor);
    bcur_init_kernel<<<2, 256, 0, stream>>>(rp0, bcur);
    edge_partition_kernel<<<g(E0, PB_CH), 256, 0, stream>>>(src0, dst0, E0, bcur, pairBuf);
    bucket_csr_fill_kernel<<<NB, 256, 0, stream>>>(pairBuf, rp0, N0, cols0, cursor);

    // ---- Layer 1 ----
    aggregate_kernel<128><<<g(N0, 8), 256, 0, stream>>>(rp0, cols0, xf, aggHi, aggLo, N0);
    linear_mfma_kernel<128, 128><<<g(N0, 64), 256, 0, stream>>>(N0, aggHi, aggLo, w1rHi, w1rLo,
                                                                xHi, xLo, w1tHi, w1tLo, b1f, x1f);

    // ---- Pool 1 (radix-select top-K1, monotonic compaction) ----
    score_kernel<128><<<g(N0, 4), 256, 0, stream>>>(x1f, p1f, N0, score, keys);
    for (int pass = 0; pass < 4; ++pass) {
        radix_hist_kernel<<<64, 256, 0, stream>>>(keys, N0, hist, ctl, pass);
        radix_select_kernel<<<1, 1024, 0, stream>>>(hist, ctl, K1, pass);
    }
    mark_keep_kernel<<<g(N0, 256), 256, 0, stream>>>(keys, N0, ctl, keep);
    run_scan(keep, N0, pos, nullptr);
    finalize_map_kernel<<<g(N0, 256), 256, 0, stream>>>(keep, pos, N0, perm1, map1);
    pool_apply_kernel<128><<<g((long long)K1 * 32, 256), 256, 0, stream>>>(x1f, score, perm1, xp1f, xp1Hi, xp1Lo, K1);

    // ---- CSR graph1 (filter CSR graph0 through map1) ----
    deg_filter_kernel<<<g(N0, 256), 256, 0, stream>>>(rp0, cols0, map1, N0, deg);
    run_scan(deg, K1, rp1, nullptr);
    csr_filter_fill_kernel<<<g(N0, 256), 256, 0, stream>>>(rp0, cols0, map1, N0, rp1, cols1);

    // ---- Layer 2 ----
    aggregate_kernel<128><<<g(K1, 8), 256, 0, stream>>>(rp1, cols1, xp1f, aggHi, aggLo, K1);
    linear_mfma_kernel<128, 64><<<g(K1, 64), 256, 0, stream>>>(K1, aggHi, aggLo, w2rHi, w2rLo,
                                                               xp1Hi, xp1Lo, w2tHi, w2tLo, b2f, x2f);

    // ---- Pool 2 (radix-select top-K2) ----
    score_kernel<64><<<g(K1, 4), 256, 0, stream>>>(x2f, p2f, K1, score, keys);
    for (int pass = 0; pass < 4; ++pass) {
        radix_hist_kernel<<<64, 256, 0, stream>>>(keys, K1, hist, ctl, pass);
        radix_select_kernel<<<1, 1024, 0, stream>>>(hist, ctl, K2, pass);
    }
    mark_keep_kernel<<<g(K1, 256), 256, 0, stream>>>(keys, K1, ctl, keep);
    run_scan(keep, K1, pos, nullptr);
    finalize_map_kernel<<<g(K1, 256), 256, 0, stream>>>(keep, pos, K1, perm2, map2);
    pool_apply_kernel<64><<<g((long long)K2 * 16, 256), 256, 0, stream>>>(x2f, score, perm2, xp2f, xp2Hi, xp2Lo, K2);

    // ---- CSR graph2 (filter CSR graph1 through map2) ----
    deg_filter_kernel<<<g(K1, 256), 256, 0, stream>>>(rp1, cols1, map2, K1, deg);
    run_scan(deg, K2, rp2, nullptr);
    csr_filter_fill_kernel<<<g(K1, 256), 256, 0, stream>>>(rp1, cols1, map2, K1, rp2, cols2);

    // ---- Layer 3 ----
    aggregate_kernel<64><<<g(K2, 16), 256, 0, stream>>>(rp2, cols2, xp2f, aggHi, aggLo, K2);
    linear_mfma_kernel<64, 64><<<g(K2, 64), 256, 0, stream>>>(K2, aggHi, aggLo, w3rHi, w3rLo,
                                                              xp2Hi, xp2Lo, w3tHi, w3tLo, b3f, x3f);

    // ---- Unpool 1 (in-place on x2f) ----
    unpool_add_kernel<64><<<g((long long)K1 * 16, 256), 256, 0, stream>>>(x2f, x3f, map2, u1f, u1Hi, u1Lo, K1);

    // ---- Layer 4 ----
    aggregate_kernel<64><<<g(K1, 16), 256, 0, stream>>>(rp1, cols1, u1f, aggHi, aggLo, K1);
    linear_mfma_kernel<64, 128><<<g(K1, 64), 256, 0, stream>>>(K1, aggHi, aggLo, w4rHi, w4rLo,
                                                               u1Hi, u1Lo, w4tHi, w4tLo, b4f, x4f);

    // ---- Unpool 2 (f32 in-place on x1f) ----
    unpool_add_kernel<128><<<g((long long)N0 * 32, 256), 256, 0, stream>>>(x1f, x4f, map1, x1f, u2Hi, u2Lo, N0);

    // ---- Layer 5 ----
    aggregate_kernel<128><<<g(N0, 8), 256, 0, stream>>>(rp0, cols0, x1f, aggHi, aggLo, N0);
    linear_mfma_kernel<128, 128><<<g(N0, 64), 256, 0, stream>>>(N0, aggHi, aggLo, w5rHi, w5rLo,
                                                                u2Hi, u2Lo, w5tHi, w5tLo, b5f, x5f);

    // ---- Head ----
    head_kernel<<<g(N0, 4), 256, 0, stream>>>(x5f, lwf, lbf, d_out, N0, flag);
}

// Round 5
// 1094.682 us; speedup vs baseline: 1.4505x; 1.0252x over previous
//
#include <hip/hip_runtime.h>
#include <hip/hip_bf16.h>
#include <math.h>

#define N0 50000
#define E0 1600000
#define K1 40000
#define K2 32000
#define FEAT 128
#define HID 128
#define EMB 64
#define NCLS 10

#define RADIX_BINS 4096   // 12-bit digits, 4 passes over the 48-bit key

// CSR bucketed build: 128 dsts per bucket
#define NB 391            // ceil(50000 / 128)
#define PB_CH 8192        // edges per partition block
#define BCAP 5120         // LDS staging capacity (avg bucket = 4096, +16 sigma)

#define SCHUNK 2048       // hierarchical scan: elements per block (256 thr x 8)

typedef __bf16 v8bf __attribute__((ext_vector_type(8)));
typedef __bf16 v4bf __attribute__((ext_vector_type(4)));
typedef float  v4f  __attribute__((ext_vector_type(4)));

static __device__ __forceinline__ unsigned f2key(float f) {
    unsigned u = __float_as_uint(f);
    return (u & 0x80000000u) ? ~u : (u | 0x80000000u);
}

// ---------- dtype detection ----------
__global__ void detect_dtype_kernel(const unsigned* __restrict__ w, int n, int* __restrict__ flag) {
    __shared__ int tot;
    if (threadIdx.x == 0) tot = 0;
    __syncthreads();
    int cnt = 0;
    for (int i = threadIdx.x; i < n; i += 256) {
        unsigned lo = w[i] & 0xFFFFu;
        unsigned e = (lo >> 7) & 0xFFu;
        cnt += (e >= 143);
    }
    atomicAdd(&tot, cnt);
    __syncthreads();
    if (threadIdx.x == 0) flag[0] = (tot > n / 8) ? 1 : 0;  // 1 = f32, 0 = bf16
}

static __device__ __forceinline__ float load_as_f32(const void* in, long long i, int isF32) {
    if (isF32) return ((const float*)in)[i];
    unsigned short h = ((const unsigned short*)in)[i];
    return __uint_as_float(((unsigned)h) << 16);
}

// x: one pass -> f32 SLICED [slice][row][16] + (hi,lo) row-major
__global__ void x_convert_kernel(const void* __restrict__ in, float* __restrict__ xf,
                                 __bf16* __restrict__ hi, __bf16* __restrict__ lo, int n,
                                 const int* __restrict__ flag) {
    int i = blockIdx.x * 256 + threadIdx.x;
    if (i >= n) return;
    float v = load_as_f32(in, i, *flag);
    __bf16 h = (__bf16)v;
    int row = i >> 7, c = i & 127;
    xf[(((size_t)(c >> 4)) * N0 + row) * 16 + (c & 15)] = v;
    hi[i] = h; lo[i] = (__bf16)(v - (float)h);
}

// batched weight splits (10 tensors in one launch)
struct SplitJob { const void* src; __bf16* hi; __bf16* lo; int n; };
struct SplitJobs { SplitJob j[10]; };
__global__ void split_all_kernel(SplitJobs jobs, const int* __restrict__ flag) {
    SplitJob jb = jobs.j[blockIdx.y];
    int i = blockIdx.x * 256 + threadIdx.x;
    if (i >= jb.n) return;
    float v = load_as_f32(jb.src, i, *flag);
    __bf16 h = (__bf16)v;
    jb.hi[i] = h; jb.lo[i] = (__bf16)(v - (float)h);
}

// batched small f32 conversions (9 tensors, one block each)
struct F32Job { const void* src; float* dst; int n; };
struct F32Jobs { F32Job j[9]; };
__global__ void f32_all_kernel(F32Jobs jobs, const int* __restrict__ flag) {
    F32Job jb = jobs.j[blockIdx.x];
    for (int i = threadIdx.x; i < jb.n; i += 256) jb.dst[i] = load_as_f32(jb.src, i, *flag);
}

// ---------- CSR graph0: degree count ----------
__global__ void deg_count_kernel(const int* __restrict__ dst, int E, int* __restrict__ deg) {
    int e = blockIdx.x * 256 + threadIdx.x;
    if (e >= E) return;
    atomicAdd(&deg[dst[e]], 1);
}

// ---------- hierarchical exclusive scan (3 tiny parallel launches) ----------
__global__ void scan_reduce_kernel(const int* __restrict__ deg, int M, int* __restrict__ btot) {
    int t = threadIdx.x;
    int idx = blockIdx.x * SCHUNK + t * 8;
    int s = 0;
    if (idx + 8 <= M) {
        int4 a = *(const int4*)(deg + idx);
        int4 b = *(const int4*)(deg + idx + 4);
        s = a.x + a.y + a.z + a.w + b.x + b.y + b.z + b.w;
    } else {
        for (int k = 0; k < 8; ++k) if (idx + k < M) s += deg[idx + k];
    }
    for (int off = 32; off >= 1; off >>= 1) s += __shfl_xor(s, off, 64);
    __shared__ int ws[4];
    if ((t & 63) == 0) ws[t >> 6] = s;
    __syncthreads();
    if (t == 0) btot[blockIdx.x] = ws[0] + ws[1] + ws[2] + ws[3];
}

// one wave: exclusive scan of <=64 block totals; grand total -> totPtr[0]
__global__ void scan_offsets_kernel(const int* __restrict__ btot, int nb,
                                    int* __restrict__ boff, int* __restrict__ totPtr) {
    int t = threadIdx.x;
    int v = (t < nb) ? btot[t] : 0;
    int incl = v;
    for (int off = 1; off < 64; off <<= 1) {
        int u = __shfl_up(incl, off, 64);
        if (t >= off) incl += u;
    }
    if (t < nb) boff[t] = incl - v;
    if (t == 63 && totPtr) totPtr[0] = incl;
}

__global__ void scan_apply_kernel(const int* __restrict__ deg, int M, const int* __restrict__ boff,
                                  int* __restrict__ rowptr, int* __restrict__ cursor) {
    int t = threadIdx.x;
    int lane = t & 63, wave = t >> 6;
    int idx = blockIdx.x * SCHUNK + t * 8;
    int v[8];
#pragma unroll
    for (int k = 0; k < 8; ++k) v[k] = (idx + k < M) ? deg[idx + k] : 0;
    int s = 0;
#pragma unroll
    for (int k = 0; k < 8; ++k) { int tmp = v[k]; v[k] = s; s += tmp; }  // thread-local exclusive
    int incl = s;
    for (int off = 1; off < 64; off <<= 1) {
        int u = __shfl_up(incl, off, 64);
        if (lane >= off) incl += u;
    }
    int texcl = incl - s;
    __shared__ int ws[4];
    if (lane == 63) ws[wave] = incl;
    __syncthreads();
    int woff = 0;
    for (int w = 0; w < 4; ++w) if (w < wave) woff += ws[w];
    int off0 = boff[blockIdx.x] + woff + texcl;
#pragma unroll
    for (int k = 0; k < 8; ++k) {
        int j = idx + k;
        if (j < M) {
            int val = off0 + v[k];
            rowptr[j] = val;
            if (cursor) cursor[j] = val;
        }
    }
}

// ---------- CSR graph0: bucketed two-pass fill (write line-density fix) ----------
__global__ void bcur_init_kernel(const int* __restrict__ rp, int* __restrict__ bcur) {
    int b = blockIdx.x * 256 + threadIdx.x;
    if (b < NB) bcur[b] = rp[b << 7];
}

__global__ void edge_partition_kernel(const int* __restrict__ src, const int* __restrict__ dst, int E,
                                      int* __restrict__ bcur, unsigned* __restrict__ pairBuf) {
    __shared__ int cnt[NB];
    __shared__ int bas[NB];
    for (int b = threadIdx.x; b < NB; b += 256) cnt[b] = 0;
    __syncthreads();
    int e0 = blockIdx.x * PB_CH;
    int e1 = E < e0 + PB_CH ? E : e0 + PB_CH;
    for (int e = e0 + threadIdx.x; e < e1; e += 256)
        atomicAdd(&cnt[dst[e] >> 7], 1);
    __syncthreads();
    for (int b = threadIdx.x; b < NB; b += 256) {
        int c = cnt[b];
        bas[b] = c ? atomicAdd(&bcur[b], c) : 0;
        cnt[b] = 0;
    }
    __syncthreads();
    for (int e = e0 + threadIdx.x; e < e1; e += 256) {
        int s = src[e], d = dst[e];
        int b = d >> 7;
        int r = atomicAdd(&cnt[b], 1);
        pairBuf[bas[b] + r] = ((unsigned)(d & 127) << 16) | (unsigned)s;  // both < 65536
    }
}

__global__ void bucket_csr_fill_kernel(const unsigned* __restrict__ pairBuf, const int* __restrict__ rp,
                                       int Mrows, int* __restrict__ cols, int* __restrict__ gcursor) {
    int b = blockIdx.x;
    int d0 = b << 7;
    int d1 = d0 + 128; if (d1 > Mrows) d1 = Mrows;
    int segBase = rp[d0], segEnd = rp[d1];
    int size = segEnd - segBase;
    __shared__ int cur[128];
    __shared__ int stage[BCAP];
    if (size <= BCAP) {
        for (int j = threadIdx.x; j < d1 - d0; j += 256) cur[j] = rp[d0 + j] - segBase;
        __syncthreads();
        for (int t = threadIdx.x; t < size; t += 256) {
            unsigned p = pairBuf[segBase + t];
            int pos = atomicAdd(&cur[p >> 16], 1);
            stage[pos] = (int)(p & 0xFFFFu);
        }
        __syncthreads();
        for (int t = threadIdx.x; t < size; t += 256) cols[segBase + t] = stage[t];
    } else {  // statistically unreachable; correctness fallback
        for (int t = threadIdx.x; t < size; t += 256) {
            unsigned p = pairBuf[segBase + t];
            int pos = atomicAdd(&gcursor[d0 + (int)(p >> 16)], 1);
            cols[pos] = (int)(p & 0xFFFFu);
        }
    }
}

// ---------- CSR graph k+1 from CSR k (filter through monotonic mapping) ----------
__global__ void deg_filter_kernel(const int* __restrict__ rowptr, const int* __restrict__ cols,
                                  const int* __restrict__ map, int Mold, int* __restrict__ deg) {
    int d = blockIdx.x * 256 + threadIdx.x;
    if (d >= Mold) return;
    int nd = map[d];
    if (nd < 0) return;
    int b = rowptr[d], e = rowptr[d + 1];
    int c = 0;
    for (int j = b; j < e; ++j) c += (map[cols[j]] >= 0);
    deg[nd] = c;
}

__global__ void csr_filter_fill_kernel(const int* __restrict__ rowptr, const int* __restrict__ cols,
                                       const int* __restrict__ map, int Mold,
                                       const int* __restrict__ newrp, int* __restrict__ ncols) {
    int d = blockIdx.x * 256 + threadIdx.x;
    if (d >= Mold) return;
    int nd = map[d];
    if (nd < 0) return;
    int w = newrp[nd];
    int b = rowptr[d], e = rowptr[d + 1];
    for (int j = b; j < e; ++j) {
        int ns = map[cols[j]];
        if (ns >= 0) ncols[w++] = ns;
    }
}

// ---------- gather aggregation (XCD feature-sliced) ----------
// Source xs is SLICED [8][M][SW] (SW = C/8 floats). blockIdx.x & 7 selects the
// slice; with round-robin block->XCD dispatch, each XCD's gather working set is
// M*SW*4B (<=3.2MB) and stays resident in its private 4MB L2 (was 347MB HBM
// fetch/dispatch at row-major). Output agg is sliced the same way.
template<int C>
__global__ void aggregate_kernel(const int* __restrict__ rowptr, const int* __restrict__ cols,
                                 const float* __restrict__ xs, __bf16* __restrict__ aggHi,
                                 __bf16* __restrict__ aggLo, int M) {
    const int SW = C / 8;          // slice width in floats (16 or 8)
    const int LPR = SW / 4;        // lanes per row (4 or 2)
    const int RPB = 256 / LPR;     // rows per block (64 or 128)
    int sl = blockIdx.x & 7;
    int n  = (blockIdx.x >> 3) * RPB + threadIdx.x / LPR;
    int c4 = threadIdx.x % LPR;
    if (n >= M) return;
    const float* xsl = xs + (size_t)sl * M * SW + (size_t)c4 * 4;
    int b = rowptr[n], e = rowptr[n + 1];
    float4 s = {0.f, 0.f, 0.f, 0.f};
    int j = b;
    for (; j + 2 <= e; j += 2) {               // 2x unroll: two loads in flight
        int s0 = cols[j], s1 = cols[j + 1];
        float4 v0 = *(const float4*)(xsl + (size_t)s0 * SW);
        float4 v1 = *(const float4*)(xsl + (size_t)s1 * SW);
        s.x += v0.x; s.y += v0.y; s.z += v0.z; s.w += v0.w;
        s.x += v1.x; s.y += v1.y; s.z += v1.z; s.w += v1.w;
    }
    if (j < e) {
        int s0 = cols[j];
        float4 v0 = *(const float4*)(xsl + (size_t)s0 * SW);
        s.x += v0.x; s.y += v0.y; s.z += v0.z; s.w += v0.w;
    }
    v4bf h, l;
    h[0] = (__bf16)s.x; l[0] = (__bf16)(s.x - (float)h[0]);
    h[1] = (__bf16)s.y; l[1] = (__bf16)(s.y - (float)h[1]);
    h[2] = (__bf16)s.z; l[2] = (__bf16)(s.z - (float)h[2]);
    h[3] = (__bf16)s.w; l[3] = (__bf16)(s.w - (float)h[3]);
    size_t o = ((size_t)sl * M + n) * SW + c4 * 4;
    *(v4bf*)(aggHi + o) = h;
    *(v4bf*)(aggLo + o) = l;
}

// ---------- split-precision MFMA dual linear + bias + relu ----------
// A-operand (agg) is sliced [8][M][SW]; B-operand (root features) is row-major.
template<int Cin, int Cout>
__global__ void linear_mfma_kernel(int M,
                                   const __bf16* __restrict__ Ahi, const __bf16* __restrict__ Alo,
                                   const __bf16* __restrict__ WaHi, const __bf16* __restrict__ WaLo,
                                   const __bf16* __restrict__ Bhi, const __bf16* __restrict__ Blo,
                                   const __bf16* __restrict__ WbHi, const __bf16* __restrict__ WbLo,
                                   const float* __restrict__ bias, float* __restrict__ outF) {
    constexpr int NG = Cout / 16;
    constexpr int SW = Cin / 8;
    int wave = threadIdx.x >> 6;
    int lane = threadIdx.x & 63;
    int m = lane & 15, quad = lane >> 4;
    int row0 = blockIdx.x * 64 + wave * 16;
    int ra = row0 + m; if (ra > M - 1) ra = M - 1;

    v4f acc[NG];
#pragma unroll
    for (int g = 0; g < NG; ++g) acc[g] = (v4f){0.f, 0.f, 0.f, 0.f};

#pragma unroll
    for (int ks = 0; ks < Cin / 32; ++ks) {
        int col0 = ks * 32 + quad * 8;
        int sl = col0 / SW, off = col0 % SW;
        size_t aoff = ((size_t)sl * M + ra) * SW + off;   // sliced A
        v8bf ah = *(const v8bf*)(Ahi + aoff);
        v8bf al = *(const v8bf*)(Alo + aoff);
#pragma unroll
        for (int g = 0; g < NG; ++g) {
            size_t woff = (size_t)(g * 16 + m) * Cin + ks * 32 + quad * 8;
            v8bf bh = *(const v8bf*)(WaHi + woff);
            v8bf bl = *(const v8bf*)(WaLo + woff);
            acc[g] = __builtin_amdgcn_mfma_f32_16x16x32_bf16(ah, bh, acc[g], 0, 0, 0);
            acc[g] = __builtin_amdgcn_mfma_f32_16x16x32_bf16(ah, bl, acc[g], 0, 0, 0);
            acc[g] = __builtin_amdgcn_mfma_f32_16x16x32_bf16(al, bh, acc[g], 0, 0, 0);
        }
    }
#pragma unroll
    for (int ks = 0; ks < Cin / 32; ++ks) {
        size_t aoff = (size_t)ra * Cin + ks * 32 + quad * 8;  // row-major B
        v8bf ah = *(const v8bf*)(Bhi + aoff);
        v8bf al = *(const v8bf*)(Blo + aoff);
#pragma unroll
        for (int g = 0; g < NG; ++g) {
            size_t woff = (size_t)(g * 16 + m) * Cin + ks * 32 + quad * 8;
            v8bf bh = *(const v8bf*)(WbHi + woff);
            v8bf bl = *(const v8bf*)(WbLo + woff);
            acc[g] = __builtin_amdgcn_mfma_f32_16x16x32_bf16(ah, bh, acc[g], 0, 0, 0);
            acc[g] = __builtin_amdgcn_mfma_f32_16x16x32_bf16(ah, bl, acc[g], 0, 0, 0);
            acc[g] = __builtin_amdgcn_mfma_f32_16x16x32_bf16(al, bh, acc[g], 0, 0, 0);
        }
    }

    // C/D layout: col = lane&15, row = quad*4 + reg
#pragma unroll
    for (int g = 0; g < NG; ++g) {
        int col = g * 16 + m;
        float bv = bias[col];
#pragma unroll
        for (int r = 0; r < 4; ++r) {
            int row = row0 + quad * 4 + r;
            if (row < M) outF[(size_t)row * Cout + col] = fmaxf(acc[g][r] + bv, 0.f);
        }
    }
}

// ---------- pooling score (fused 48-bit selection key build) ----------
// key = (f2key(score) << 16) | (~i & 0xFFFF)   -- valid since N <= 65536;
// preserves exact smaller-index-first tie-break of jax.lax.top_k.
template<int C>
__global__ void score_kernel(const float* __restrict__ xin, const float* __restrict__ w,
                             int M, float* __restrict__ score, unsigned long long* __restrict__ keys) {
    int row = blockIdx.x * 4 + (threadIdx.x >> 6);
    int lane = threadIdx.x & 63;
    if (row >= M) return;
    float p = 0.f, q = 0.f;
#pragma unroll
    for (int c = lane; c < C; c += 64) {
        float wc = w[c];
        float xc = xin[(size_t)row * C + c];
        p += xc * wc; q += wc * wc;
    }
#pragma unroll
    for (int off = 32; off >= 1; off >>= 1) {
        p += __shfl_xor(p, off, 64);
        q += __shfl_xor(q, off, 64);
    }
    if (lane == 0) {
        float arg = p / sqrtf(q);
        float sc = (float)tanh((double)arg);
        score[row] = sc;
        keys[row] = ((unsigned long long)f2key(sc) << 16) |
                    (unsigned long long)(0xFFFFu ^ (unsigned)row);
    }
}

// ---------- radix-select top-K threshold (4 passes of 12-bit digits on 48-bit keys) ----------
struct SelCtl { unsigned long long prefix; int kRem; int counter; };

__global__ void radix_hist_kernel(const unsigned long long* __restrict__ keys, int N,
                                  int* __restrict__ hist, const SelCtl* __restrict__ ctl, int pass) {
    __shared__ int lh[RADIX_BINS];
    for (int b = threadIdx.x; b < RADIX_BINS; b += 256) lh[b] = 0;
    __syncthreads();
    int shift = 36 - 12 * pass;                 // pass0: bits[36:48) ... pass3: bits[0:12)
    unsigned long long pref = (pass > 0) ? ctl->prefix : 0ull;
    for (int i = blockIdx.x * 256 + threadIdx.x; i < N; i += gridDim.x * 256) {
        unsigned long long key = keys[i];
        if (pass > 0 && (key >> (shift + 12)) != pref) continue;
        atomicAdd(&lh[(int)((key >> shift) & 0xFFFull)], 1);
    }
    __syncthreads();
    for (int b = threadIdx.x; b < RADIX_BINS; b += 256) {
        int c = lh[b];
        if (c) atomicAdd(&hist[b], c);          // <=gridDim adds per address
    }
}

__global__ void radix_select_kernel(int* __restrict__ hist, SelCtl* __restrict__ ctl,
                                    int K, int pass) {
    __shared__ int part[1024];
    int t = threadIdx.x;
    int kRem = (pass == 0) ? K : ctl->kRem;
    unsigned long long oldPrefix = (pass == 0) ? 0ull : ctl->prefix;
    int base = t * 4;
    int h0 = hist[base], h1 = hist[base + 1], h2 = hist[base + 2], h3 = hist[base + 3];
    int tot = h0 + h1 + h2 + h3;
    part[t] = tot;
    __syncthreads();
    // inclusive suffix sum: part[t] = sum_{t' >= t} tot(t')
    for (int off = 1; off < 1024; off <<= 1) {
        int v = (t + off < 1024) ? part[t + off] : 0;
        __syncthreads();
        part[t] += v;
        __syncthreads();
    }
    int sExcl = part[t] - tot;                  // keys with digit in a strictly higher chunk
    if (sExcl < kRem && kRem <= sExcl + tot) {  // crossing chunk (unique; tot>0 here)
        int c = sExcl;
        int hv[4] = {h0, h1, h2, h3};
        for (int k = 3; k >= 0; --k) {
            int h = hv[k];
            if (c + h >= kRem) {
                ctl->prefix = (oldPrefix << 12) | (unsigned long long)(base + k);
                ctl->kRem = kRem - c;
                ctl->counter = 0;
                break;
            }
            c += h;
        }
    }
    // re-zero for the next histogram pass
    hist[base] = 0; hist[base + 1] = 0; hist[base + 2] = 0; hist[base + 3] = 0;
}

// ---------- monotonic keep/compact (makes CSR-filter writes sequential) ----------
__global__ void mark_keep_kernel(const unsigned long long* __restrict__ keys, int N,
                                 const SelCtl* __restrict__ ctl, int* __restrict__ keep) {
    int i = blockIdx.x * 256 + threadIdx.x;
    if (i < N) keep[i] = (keys[i] >= ctl->prefix) ? 1 : 0;
}

__global__ void finalize_map_kernel(const int* __restrict__ keep, const int* __restrict__ pos,
                                    int N, int* __restrict__ perm, int* __restrict__ mapping) {
    int i = blockIdx.x * 256 + threadIdx.x;
    if (i >= N) return;
    if (keep[i]) { int r = pos[i]; perm[r] = i; mapping[i] = r; }
    else mapping[i] = -1;
}

// xp[j] = x[perm[j]] * score[perm[j]]  -> f32 SLICED + (hi,lo) row-major
template<int C>
__global__ void pool_apply_kernel(const float* __restrict__ xin, const float* __restrict__ score,
                                  const int* __restrict__ perm, float* __restrict__ xpF,
                                  __bf16* __restrict__ xpHi, __bf16* __restrict__ xpLo, int K) {
    const int CH = C / 4;
    const int SW = C / 8;
    int tid = blockIdx.x * 256 + threadIdx.x;
    int j = tid / CH, c4 = tid % CH;
    if (j >= K) return;
    int src = perm[j];
    float s = score[src];
    float4 v = ((const float4*)(xin + (size_t)src * C))[c4];
    v.x *= s; v.y *= s; v.z *= s; v.w *= s;
    int sl = (c4 * 4) / SW, off = (c4 * 4) % SW;
    *(float4*)(xpF + ((size_t)sl * K + j) * SW + off) = v;
    v4bf h, l;
    h[0] = (__bf16)v.x; l[0] = (__bf16)(v.x - (float)h[0]);
    h[1] = (__bf16)v.y; l[1] = (__bf16)(v.y - (float)h[1]);
    h[2] = (__bf16)v.z; l[2] = (__bf16)(v.z - (float)h[2]);
    h[3] = (__bf16)v.w; l[3] = (__bf16)(v.w - (float)h[3]);
    *(v4bf*)(xpHi + (size_t)j * C + c4 * 4) = h;
    *(v4bf*)(xpLo + (size_t)j * C + c4 * 4) = l;
}

// u[j] = base[j] + (mapping[j]>=0 ? deep[mapping[j]] : 0)
// base/deep row-major; uF written SLICED (separate buffer); hi/lo row-major.
template<int C>
__global__ void unpool_add_kernel(const float* __restrict__ base, const float* __restrict__ deep,
                                  const int* __restrict__ mapping, float* __restrict__ uF,
                                  __bf16* __restrict__ uHi, __bf16* __restrict__ uLo, int M) {
    const int CH = C / 4;
    const int SW = C / 8;
    int tid = blockIdx.x * 256 + threadIdx.x;
    int j = tid / CH, c4 = tid % CH;
    if (j >= M) return;
    float4 v = ((const float4*)(base + (size_t)j * C))[c4];
    int m = mapping[j];
    if (m >= 0) {
        float4 d = ((const float4*)(deep + (size_t)m * C))[c4];
        v.x += d.x; v.y += d.y; v.z += d.z; v.w += d.w;
    }
    int sl = (c4 * 4) / SW, off = (c4 * 4) % SW;
    *(float4*)(uF + ((size_t)sl * M + j) * SW + off) = v;
    v4bf h, l;
    h[0] = (__bf16)v.x; l[0] = (__bf16)(v.x - (float)h[0]);
    h[1] = (__bf16)v.y; l[1] = (__bf16)(v.y - (float)h[1]);
    h[2] = (__bf16)v.z; l[2] = (__bf16)(v.z - (float)h[2]);
    h[3] = (__bf16)v.w; l[3] = (__bf16)(v.w - (float)h[3]);
    *(v4bf*)(uHi + (size_t)j * C + c4 * 4) = h;
    *(v4bf*)(uLo + (size_t)j * C + c4 * 4) = l;
}

__global__ void head_kernel(const float* __restrict__ x5, const float* __restrict__ lw,
                            const float* __restrict__ lb, void* __restrict__ out, int M,
                            const int* __restrict__ flag) {
    int row = blockIdx.x * 4 + (threadIdx.x >> 6);
    int lane = threadIdx.x & 63;
    if (row >= M) return;
    float a0 = x5[(size_t)row * 128 + lane];
    float a1 = x5[(size_t)row * 128 + 64 + lane];
    float d[NCLS];
#pragma unroll
    for (int o = 0; o < NCLS; ++o) {
        float p = a0 * lw[o * 128 + lane] + a1 * lw[o * 128 + 64 + lane];
#pragma unroll
        for (int off = 32; off >= 1; off >>= 1) p += __shfl_xor(p, off, 64);
        d[o] = p + lb[o];
    }
    float mx = d[0];
#pragma unroll
    for (int o = 1; o < NCLS; ++o) mx = fmaxf(mx, d[o]);
    float s = 0.f;
#pragma unroll
    for (int o = 0; o < NCLS; ++o) s += expf(d[o] - mx);
    float lse = mx + logf(s);
    if (lane < NCLS) {
        float v = d[0];
#pragma unroll
        for (int o = 1; o < NCLS; ++o) if (lane == o) v = d[o];
        float r = v - lse;
        if (*flag) ((float*)out)[(size_t)row * NCLS + lane] = r;
        else ((__hip_bfloat16*)out)[(size_t)row * NCLS + lane] = __float2bfloat16(r);
    }
}

extern "C" void kernel_launch(void* const* d_in, const int* in_sizes, int n_in,
                              void* d_out, int out_size, void* d_ws, size_t ws_size,
                              hipStream_t stream) {
    const void* x_raw   = d_in[0];
    const int*  ei      = (const int*)d_in[1];
    const void* w1_rel  = d_in[2];
    const void* w1_root = d_in[3];
    const void* b1      = d_in[4];
    const void* p1w     = d_in[5];
    const void* w2_rel  = d_in[6];
    const void* w2_root = d_in[7];
    const void* b2      = d_in[8];
    const void* p2w     = d_in[9];
    const void* w3_rel  = d_in[10];
    const void* w3_root = d_in[11];
    const void* b3      = d_in[12];
    const void* w4_rel  = d_in[13];
    const void* w4_root = d_in[14];
    const void* b4      = d_in[15];
    const void* w5_rel  = d_in[16];
    const void* w5_root = d_in[17];
    const void* b5      = d_in[18];
    const void* lw      = d_in[19];
    const void* lb      = d_in[20];

    char* base = (char*)d_ws;
    size_t off = 0;
    auto alloc = [&](size_t bytes) -> void* {
        void* p = base + off;
        off = (off + bytes + 255) & ~(size_t)255;
        return p;
    };
    int* flag = (int*)alloc(256);
    __bf16* w1rHi = (__bf16*)alloc(HID * FEAT * 2); __bf16* w1rLo = (__bf16*)alloc(HID * FEAT * 2);
    __bf16* w1tHi = (__bf16*)alloc(HID * FEAT * 2); __bf16* w1tLo = (__bf16*)alloc(HID * FEAT * 2);
    __bf16* w2rHi = (__bf16*)alloc(EMB * HID * 2);  __bf16* w2rLo = (__bf16*)alloc(EMB * HID * 2);
    __bf16* w2tHi = (__bf16*)alloc(EMB * HID * 2);  __bf16* w2tLo = (__bf16*)alloc(EMB * HID * 2);
    __bf16* w3rHi = (__bf16*)alloc(EMB * EMB * 2);  __bf16* w3rLo = (__bf16*)alloc(EMB * EMB * 2);
    __bf16* w3tHi = (__bf16*)alloc(EMB * EMB * 2);  __bf16* w3tLo = (__bf16*)alloc(EMB * EMB * 2);
    __bf16* w4rHi = (__bf16*)alloc(HID * EMB * 2);  __bf16* w4rLo = (__bf16*)alloc(HID * EMB * 2);
    __bf16* w4tHi = (__bf16*)alloc(HID * EMB * 2);  __bf16* w4tLo = (__bf16*)alloc(HID * EMB * 2);
    __bf16* w5rHi = (__bf16*)alloc(FEAT * HID * 2); __bf16* w5rLo = (__bf16*)alloc(FEAT * HID * 2);
    __bf16* w5tHi = (__bf16*)alloc(FEAT * HID * 2); __bf16* w5tLo = (__bf16*)alloc(FEAT * HID * 2);
    float* b1f = (float*)alloc(HID * 4);
    float* b2f = (float*)alloc(EMB * 4);
    float* b3f = (float*)alloc(EMB * 4);
    float* b4f = (float*)alloc(HID * 4);
    float* b5f = (float*)alloc(FEAT * 4);
    float* p1f = (float*)alloc(HID * 4);
    float* p2f = (float*)alloc(EMB * 4);
    float* lwf = (float*)alloc(NCLS * FEAT * 4);
    float* lbf = (float*)alloc(NCLS * 4);
    float* score = (float*)alloc((size_t)N0 * 4);
    unsigned long long* keys = (unsigned long long*)alloc((size_t)N0 * 8);
    int* hist = (int*)alloc((size_t)RADIX_BINS * 4);
    SelCtl* ctl = (SelCtl*)alloc(256);
    int* btot = (int*)alloc(64 * 4);
    int* boff = (int*)alloc(64 * 4);
    int* perm1 = (int*)alloc((size_t)K1 * 4);
    int* map1  = (int*)alloc((size_t)N0 * 4);
    int* perm2 = (int*)alloc((size_t)K2 * 4);
    int* map2  = (int*)alloc((size_t)K1 * 4);
    int* keep  = (int*)alloc((size_t)(N0 + 1) * 4);
    int* pos   = (int*)alloc((size_t)(N0 + 1) * 4);
    int* deg   = (int*)alloc((size_t)(N0 + 1) * 4);
    int* cursor= (int*)alloc((size_t)(N0 + 1) * 4);
    int* rp0   = (int*)alloc((size_t)(N0 + 1) * 4);
    int* rp1   = (int*)alloc((size_t)(K1 + 1) * 4);
    int* rp2   = (int*)alloc((size_t)(K2 + 1) * 4);
    int* bcur  = (int*)alloc((size_t)NB * 4);
    int* cols0 = (int*)alloc((size_t)E0 * 4);
    int* cols1 = (int*)alloc((size_t)E0 * 4);
    int* cols2 = (int*)alloc((size_t)E0 * 4);
    // pairBuf (CSR build, dead before layer 1) shares a region with the sliced
    // unpool outputs u1s/u2s (written at unpool time).
    char* ubuf = (char*)alloc((size_t)K1 * 64 * 4 + (size_t)N0 * 128 * 4);
    unsigned* pairBuf = (unsigned*)ubuf;
    float* u1s = (float*)ubuf;                               // [8][K1][8]
    float* u2s = (float*)(ubuf + (size_t)K1 * 64 * 4);       // [8][N0][16]
    // aliased activation arenas
    char*   arenaX  = (char*)alloc((size_t)N0 * 128 * 4);   // xf -> xp1f -> xp2f -> x4f -> x5f (+x3f high)
    __bf16* arenaHi = (__bf16*)alloc((size_t)N0 * 128 * 2);
    __bf16* arenaLo = (__bf16*)alloc((size_t)N0 * 128 * 2);
    __bf16* aggHi   = (__bf16*)alloc((size_t)N0 * 128 * 2);
    __bf16* aggLo   = (__bf16*)alloc((size_t)N0 * 128 * 2);
    float*  x1f     = (float*)alloc((size_t)N0 * 128 * 4);  // linear1 out (row-major), persists
    float*  x2f     = (float*)alloc((size_t)K1 * 64 * 4);   // linear2 out (row-major), persists

    float* xf   = (float*)arenaX;                 // sliced [8][N0][16]
    float* xp1f = (float*)arenaX;                 // sliced [8][K1][16]
    float* xp2f = (float*)arenaX;                 // sliced [8][K2][8] (8.19MB)
    float* x3f  = (float*)(arenaX + 8388608);     // row-major K2 x 64
    float* x4f  = (float*)arenaX;                 // row-major K1 x 128
    float* x5f  = (float*)arenaX;                 // row-major N0 x 128
    __bf16 *xHi = arenaHi,  *xLo = arenaLo;
    __bf16 *xp1Hi = arenaHi, *xp1Lo = arenaLo;
    __bf16 *xp2Hi = arenaHi, *xp2Lo = arenaLo;
    __bf16 *u1Hi = arenaHi,  *u1Lo = arenaLo;
    __bf16 *u2Hi = arenaHi,  *u2Lo = arenaLo;

    const int* src0 = ei;
    const int* dst0 = ei + E0;

    auto g = [](long long n, int b) -> unsigned { return (unsigned)((n + b - 1) / b); };

    // hierarchical exclusive scan: deg[M] -> rowp[0..M] (+optional cursor copy)
    auto run_scan = [&](const int* degp, int M, int* rowp, int* curp) {
        int nb = (M + SCHUNK - 1) / SCHUNK;
        scan_reduce_kernel<<<nb, 256, 0, stream>>>(degp, M, btot);
        scan_offsets_kernel<<<1, 64, 0, stream>>>(btot, nb, boff, rowp + M);
        scan_apply_kernel<<<nb, 256, 0, stream>>>(degp, M, boff, rowp, curp);
    };

    // ---- dtype detect + fused conversions ----
    detect_dtype_kernel<<<1, 256, 0, stream>>>((const unsigned*)x_raw, 4096, flag);
    hipMemsetAsync(hist, 0, (size_t)RADIX_BINS * 4, stream);  // selects re-zero after each pass
    x_convert_kernel<<<g((long long)N0 * FEAT, 256), 256, 0, stream>>>(x_raw, xf, xHi, xLo, N0 * FEAT, flag);
    {
        SplitJobs sj;
        sj.j[0] = {w1_rel,  w1rHi, w1rLo, HID * FEAT};
        sj.j[1] = {w1_root, w1tHi, w1tLo, HID * FEAT};
        sj.j[2] = {w2_rel,  w2rHi, w2rLo, EMB * HID};
        sj.j[3] = {w2_root, w2tHi, w2tLo, EMB * HID};
        sj.j[4] = {w3_rel,  w3rHi, w3rLo, EMB * EMB};
        sj.j[5] = {w3_root, w3tHi, w3tLo, EMB * EMB};
        sj.j[6] = {w4_rel,  w4rHi, w4rLo, HID * EMB};
        sj.j[7] = {w4_root, w4tHi, w4tLo, HID * EMB};
        sj.j[8] = {w5_rel,  w5rHi, w5rLo, FEAT * HID};
        sj.j[9] = {w5_root, w5tHi, w5tLo, FEAT * HID};
        dim3 grid(g(HID * FEAT, 256), 10);
        split_all_kernel<<<grid, 256, 0, stream>>>(sj, flag);
    }
    {
        F32Jobs fj;
        fj.j[0] = {b1, b1f, HID};
        fj.j[1] = {b2, b2f, EMB};
        fj.j[2] = {b3, b3f, EMB};
        fj.j[3] = {b4, b4f, HID};
        fj.j[4] = {b5, b5f, FEAT};
        fj.j[5] = {p1w, p1f, HID};
        fj.j[6] = {p2w, p2f, EMB};
        fj.j[7] = {lw, lwf, NCLS * FEAT};
        fj.j[8] = {lb, lbf, NCLS};
        f32_all_kernel<<<9, 256, 0, stream>>>(fj, flag);
    }

    // ---- CSR graph0 (bucketed two-pass build) ----
    hipMemsetAsync(deg, 0, (size_t)N0 * 4, stream);
    deg_count_kernel<<<g(E0, 256), 256, 0, stream>>>(dst0, E0, deg);
    run_scan(deg, N0, rp0, cursor);
    bcur_init_kernel<<<2, 256, 0, stream>>>(rp0, bcur);
    edge_partition_kernel<<<g(E0, PB_CH), 256, 0, stream>>>(src0, dst0, E0, bcur, pairBuf);
    bucket_csr_fill_kernel<<<NB, 256, 0, stream>>>(pairBuf, rp0, N0, cols0, cursor);

    // ---- Layer 1 ----
    aggregate_kernel<128><<<g(N0, 64) * 8, 256, 0, stream>>>(rp0, cols0, xf, aggHi, aggLo, N0);
    linear_mfma_kernel<128, 128><<<g(N0, 64), 256, 0, stream>>>(N0, aggHi, aggLo, w1rHi, w1rLo,
                                                                xHi, xLo, w1tHi, w1tLo, b1f, x1f);

    // ---- Pool 1 (radix-select top-K1, monotonic compaction) ----
    score_kernel<128><<<g(N0, 4), 256, 0, stream>>>(x1f, p1f, N0, score, keys);
    for (int pass = 0; pass < 4; ++pass) {
        radix_hist_kernel<<<64, 256, 0, stream>>>(keys, N0, hist, ctl, pass);
        radix_select_kernel<<<1, 1024, 0, stream>>>(hist, ctl, K1, pass);
    }
    mark_keep_kernel<<<g(N0, 256), 256, 0, stream>>>(keys, N0, ctl, keep);
    run_scan(keep, N0, pos, nullptr);
    finalize_map_kernel<<<g(N0, 256), 256, 0, stream>>>(keep, pos, N0, perm1, map1);
    pool_apply_kernel<128><<<g((long long)K1 * 32, 256), 256, 0, stream>>>(x1f, score, perm1, xp1f, xp1Hi, xp1Lo, K1);

    // ---- CSR graph1 (filter CSR graph0 through map1) ----
    deg_filter_kernel<<<g(N0, 256), 256, 0, stream>>>(rp0, cols0, map1, N0, deg);
    run_scan(deg, K1, rp1, nullptr);
    csr_filter_fill_kernel<<<g(N0, 256), 256, 0, stream>>>(rp0, cols0, map1, N0, rp1, cols1);

    // ---- Layer 2 ----
    aggregate_kernel<128><<<g(K1, 64) * 8, 256, 0, stream>>>(rp1, cols1, xp1f, aggHi, aggLo, K1);
    linear_mfma_kernel<128, 64><<<g(K1, 64), 256, 0, stream>>>(K1, aggHi, aggLo, w2rHi, w2rLo,
                                                               xp1Hi, xp1Lo, w2tHi, w2tLo, b2f, x2f);

    // ---- Pool 2 (radix-select top-K2) ----
    score_kernel<64><<<g(K1, 4), 256, 0, stream>>>(x2f, p2f, K1, score, keys);
    for (int pass = 0; pass < 4; ++pass) {
        radix_hist_kernel<<<64, 256, 0, stream>>>(keys, K1, hist, ctl, pass);
        radix_select_kernel<<<1, 1024, 0, stream>>>(hist, ctl, K2, pass);
    }
    mark_keep_kernel<<<g(K1, 256), 256, 0, stream>>>(keys, K1, ctl, keep);
    run_scan(keep, K1, pos, nullptr);
    finalize_map_kernel<<<g(K1, 256), 256, 0, stream>>>(keep, pos, K1, perm2, map2);
    pool_apply_kernel<64><<<g((long long)K2 * 16, 256), 256, 0, stream>>>(x2f, score, perm2, xp2f, xp2Hi, xp2Lo, K2);

    // ---- CSR graph2 (filter CSR graph1 through map2) ----
    deg_filter_kernel<<<g(K1, 256), 256, 0, stream>>>(rp1, cols1, map2, K1, deg);
    run_scan(deg, K2, rp2, nullptr);
    csr_filter_fill_kernel<<<g(K1, 256), 256, 0, stream>>>(rp1, cols1, map2, K1, rp2, cols2);

    // ---- Layer 3 ----
    aggregate_kernel<64><<<g(K2, 128) * 8, 256, 0, stream>>>(rp2, cols2, xp2f, aggHi, aggLo, K2);
    linear_mfma_kernel<64, 64><<<g(K2, 64), 256, 0, stream>>>(K2, aggHi, aggLo, w3rHi, w3rLo,
                                                              xp2Hi, xp2Lo, w3tHi, w3tLo, b3f, x3f);

    // ---- Unpool 1 (x2f row-major in, u1s sliced out) ----
    unpool_add_kernel<64><<<g((long long)K1 * 16, 256), 256, 0, stream>>>(x2f, x3f, map2, u1s, u1Hi, u1Lo, K1);

    // ---- Layer 4 ----
    aggregate_kernel<64><<<g(K1, 128) * 8, 256, 0, stream>>>(rp1, cols1, u1s, aggHi, aggLo, K1);
    linear_mfma_kernel<64, 128><<<g(K1, 64), 256, 0, stream>>>(K1, aggHi, aggLo, w4rHi, w4rLo,
                                                               u1Hi, u1Lo, w4tHi, w4tLo, b4f, x4f);

    // ---- Unpool 2 (x1f row-major in, u2s sliced out) ----
    unpool_add_kernel<128><<<g((long long)N0 * 32, 256), 256, 0, stream>>>(x1f, x4f, map1, u2s, u2Hi, u2Lo, N0);

    // ---- Layer 5 ----
    aggregate_kernel<128><<<g(N0, 64) * 8, 256, 0, stream>>>(rp0, cols0, u2s, aggHi, aggLo, N0);
    linear_mfma_kernel<128, 128><<<g(N0, 64), 256, 0, stream>>>(N0, aggHi, aggLo, w5rHi, w5rLo,
                                                                u2Hi, u2Lo, w5tHi, w5tLo, b5f, x5f);

    // ---- Head ----
    head_kernel<<<g(N0, 4), 256, 0, stream>>>(x5f, lwf, lbf, d_out, N0, flag);
}